// Round 1
// baseline (650.668 us; speedup 1.0000x reference)
//
#include <hip/hip_runtime.h>
#include <math.h>

#define NH   8
#define SEQ  2048
#define DIM  512
#define EMB  512
#define DH   64
#define HALF 128
#define QT   32
#define KW   (QT + 2*HALF)   // 288

// C[M,N] = A[M,K] @ B[N,K]^T + bias[N]   (A,B row-major)
template<int BM, int BN, int BK>
__global__ __launch_bounds__(256)
void gemm_nt(const float* __restrict__ A, const float* __restrict__ B,
             const float* __restrict__ bias, float* __restrict__ C,
             int M, int N, int K) {
    __shared__ float As[BK][BM + 1];
    __shared__ float Bs[BK][BN + 1];
    const int bm = blockIdx.y * BM, bn = blockIdx.x * BN;
    const int tid = threadIdx.x;
    const int tx = tid % 16, ty = tid / 16;
    float c[4][4] = {};
    for (int kt = 0; kt < K; kt += BK) {
        for (int i = tid; i < BM * BK; i += 256) {
            int m = i / BK, k = i % BK;
            As[k][m] = A[(size_t)(bm + m) * K + kt + k];
        }
        for (int i = tid; i < BN * BK; i += 256) {
            int n = i / BK, k = i % BK;
            Bs[k][n] = B[(size_t)(bn + n) * K + kt + k];
        }
        __syncthreads();
        #pragma unroll
        for (int k = 0; k < BK; ++k) {
            float a[4], bb[4];
            #pragma unroll
            for (int u = 0; u < 4; ++u) a[u] = As[k][ty * 4 + u];
            #pragma unroll
            for (int u = 0; u < 4; ++u) bb[u] = Bs[k][tx * 4 + u];
            #pragma unroll
            for (int u = 0; u < 4; ++u)
                #pragma unroll
                for (int v = 0; v < 4; ++v)
                    c[u][v] += a[u] * bb[v];
        }
        __syncthreads();
    }
    #pragma unroll
    for (int u = 0; u < 4; ++u)
        #pragma unroll
        for (int v = 0; v < 4; ++v) {
            int m = bm + ty * 4 + u, n = bn + tx * 4 + v;
            C[(size_t)m * N + n] = c[u][v] + bias[n];
        }
}

// One block per (b,h, 32-query tile). qkv flat layout: [B*S, 3*EMB],
// head h: q at col h*192+d, k at h*192+64+d, v at h*192+128+d.
__global__ __launch_bounds__(256)
void attn_kernel(const float* __restrict__ qkv, const int* __restrict__ pad,
                 float* __restrict__ Y) {
    const int bh = blockIdx.y;          // b*NH + h
    const int b = bh / NH, h = bh % NH;
    const int i0 = blockIdx.x * QT;
    const int kb = i0 - HALF;           // first key index of the window
    const int tid = threadIdx.x;

    __shared__ float Qs[QT][DH];
    __shared__ float Sc[QT][KW];
    __shared__ int   padq[QT];

    for (int i = tid; i < QT * DH; i += 256) {
        int q = i / DH, d = i % DH;
        Qs[q][d] = qkv[(size_t)(b * SEQ + i0 + q) * (3 * EMB) + h * (3 * DH) + d];
    }
    if (tid < QT) padq[tid] = pad[b * SEQ + i0 + tid];
    __syncthreads();

    // scores
    for (int idx = tid; idx < QT * KW; idx += 256) {
        int q = idx / KW, jl = idx % KW;
        int i = i0 + q, j = kb + jl;
        float sc = -1e30f;
        bool ok = (j >= 0) && (j < SEQ) && (j >= i - HALF) && (j <= i + HALF)
                  && padq[q] && (pad[b * SEQ + j] != 0);
        if (ok) {
            const float* kp = qkv + (size_t)(b * SEQ + j) * (3 * EMB) + h * (3 * DH) + DH;
            float s = 0.f;
            #pragma unroll
            for (int d = 0; d < DH; ++d) s += Qs[q][d] * kp[d];
            sc = s * 0.125f;   // 1/sqrt(64)
        }
        Sc[q][jl] = sc;
    }
    __syncthreads();

    // softmax: one wave per row
    const int wave = tid / 64, lane = tid % 64;
    for (int q = wave; q < QT; q += 4) {
        if (!padq[q]) {     // padded query row -> all zeros
            for (int jl = lane; jl < KW; jl += 64) Sc[q][jl] = 0.f;
            continue;
        }
        float m = -1e30f;
        for (int jl = lane; jl < KW; jl += 64) m = fmaxf(m, Sc[q][jl]);
        #pragma unroll
        for (int off = 32; off > 0; off >>= 1) m = fmaxf(m, __shfl_xor(m, off));
        float sum = 0.f;
        for (int jl = lane; jl < KW; jl += 64) {
            float e = __expf(Sc[q][jl] - m);   // masked: exp(-1e30 - m) = 0
            Sc[q][jl] = e;
            sum += e;
        }
        #pragma unroll
        for (int off = 32; off > 0; off >>= 1) sum += __shfl_xor(sum, off);
        float inv = 1.f / sum;
        for (int jl = lane; jl < KW; jl += 64) Sc[q][jl] *= inv;
    }
    __syncthreads();

    // PV: Y[32][64]
    const int jlo = (kb < 0) ? -kb : 0;
    const int jhi = (kb + KW > SEQ) ? (SEQ - kb) : KW;
    for (int idx = tid; idx < QT * DH; idx += 256) {
        int q = idx / DH, d = idx % DH;
        float acc = 0.f;
        for (int jl = jlo; jl < jhi; ++jl) {
            int j = kb + jl;
            acc += Sc[q][jl] * qkv[(size_t)(b * SEQ + j) * (3 * EMB) + h * (3 * DH) + 2 * DH + d];
        }
        Y[(size_t)(b * SEQ + i0 + q) * EMB + h * DH + d] = acc;
    }
}

extern "C" void kernel_launch(void* const* d_in, const int* in_sizes, int n_in,
                              void* d_out, int out_size, void* d_ws, size_t ws_size,
                              hipStream_t stream) {
    const float* x    = (const float*)d_in[0];
    const int*   pad  = (const int*)d_in[1];
    const float* Wqkv = (const float*)d_in[2];
    const float* bqkv = (const float*)d_in[3];
    const float* Wo   = (const float*)d_in[4];
    const float* bo   = (const float*)d_in[5];
    float* out = (float*)d_out;

    const int BS = 2 * SEQ;                 // 4096 rows
    float* qkv = (float*)d_ws;              // [4096, 1536] = 25.2 MB
    float* Yb  = qkv + (size_t)BS * (3 * EMB);  // [4096, 512] = 8.4 MB

    dim3 blk(256);
    // qkv = x @ Wqkv^T + bqkv   (M=4096, N=1536, K=512)
    gemm_nt<64, 64, 16><<<dim3((3 * EMB) / 64, BS / 64), blk, 0, stream>>>(
        x, Wqkv, bqkv, qkv, BS, 3 * EMB, DIM);
    // windowed attention -> Yb [4096, 512]
    attn_kernel<<<dim3(SEQ / QT, 2 * NH), blk, 0, stream>>>(qkv, pad, Yb);
    // out = Yb @ Wo^T + bo      (M=4096, N=512, K=512)
    gemm_nt<64, 64, 16><<<dim3(EMB / 64, BS / 64), blk, 0, stream>>>(
        Yb, Wo, bo, out, BS, EMB, DIM);
}

// Round 2
// 225.787 us; speedup vs baseline: 2.8818x; 2.8818x over previous
//
#include <hip/hip_runtime.h>
#include <math.h>

#define NH   8
#define SEQ  2048
#define DIM  512
#define EMB  512
#define DH   64
#define HALF 128
#define QT   32
#define KW   (QT + 2*HALF)   // 288

typedef __attribute__((ext_vector_type(8))) short short8;
typedef __attribute__((ext_vector_type(4))) float f32x4;

__device__ __forceinline__ unsigned short f2bf(float f) {
    unsigned int u = __float_as_uint(f);
    return (unsigned short)((u + 0x7fffu + ((u >> 16) & 1u)) >> 16);
}

__global__ __launch_bounds__(256)
void cvt_bf16(const float* __restrict__ in, unsigned short* __restrict__ out, int n4) {
    int i = blockIdx.x * blockDim.x + threadIdx.x;
    if (i >= n4) return;
    float4 v = ((const float4*)in)[i];
    ushort4 o = make_ushort4(f2bf(v.x), f2bf(v.y), f2bf(v.z), f2bf(v.w));
    ((ushort4*)out)[i] = o;
}

// C[M,N] = A[M,K] @ B[N,K]^T + bias[N];  A,B bf16 row-major, C f32.
// BM=128 fixed, 256 threads = 4 waves arranged WR x WC.
template<int BN, int WR, int WC>
__global__ __launch_bounds__(256)
void gemm_bf16(const unsigned short* __restrict__ A, const unsigned short* __restrict__ B,
               const float* __restrict__ bias, float* __restrict__ C,
               int M, int N, int K) {
    constexpr int BM = 128, BK = 32;
    constexpr int WM = BM / WR, WN = BN / WC;
    constexpr int FM = WM / 16, FN = WN / 16;
    __shared__ unsigned short As[BM * BK];
    __shared__ unsigned short Bs[BN * BK];
    const int t = threadIdx.x, lane = t & 63, wid = t >> 6;
    const int wr = wid / WC, wc = wid % WC;
    const int bm = blockIdx.y * BM, bn = blockIdx.x * BN;

    f32x4 acc[FM][FN];
    #pragma unroll
    for (int m = 0; m < FM; ++m)
        #pragma unroll
        for (int n = 0; n < FN; ++n)
            acc[m][n] = (f32x4){0.f, 0.f, 0.f, 0.f};

    const int lr = lane & 15, lk = (lane >> 4) * 8;

    for (int kt = 0; kt < K; kt += BK) {
        #pragma unroll
        for (int off = 0; off < BM * BK; off += 2048) {
            const int e = off + t * 8, r = e >> 5, c = e & 31;
            *(short8*)&As[e] = *(const short8*)(A + (size_t)(bm + r) * K + kt + c);
        }
        #pragma unroll
        for (int off = 0; off < BN * BK; off += 2048) {
            const int e = off + t * 8, r = e >> 5, c = e & 31;
            *(short8*)&Bs[e] = *(const short8*)(B + (size_t)(bn + r) * K + kt + c);
        }
        __syncthreads();
        short8 af[FM], bf[FN];
        #pragma unroll
        for (int m = 0; m < FM; ++m)
            af[m] = *(const short8*)&As[(wr * WM + m * 16 + lr) * BK + lk];
        #pragma unroll
        for (int n = 0; n < FN; ++n)
            bf[n] = *(const short8*)&Bs[(wc * WN + n * 16 + lr) * BK + lk];
        #pragma unroll
        for (int m = 0; m < FM; ++m)
            #pragma unroll
            for (int n = 0; n < FN; ++n)
                acc[m][n] = __builtin_amdgcn_mfma_f32_16x16x32_bf16(af[m], bf[n], acc[m][n], 0, 0, 0);
        __syncthreads();
    }

    const int orow = bm + wr * WM + (lane >> 4) * 4;
    const int ocol0 = bn + wc * WN + (lane & 15);
    #pragma unroll
    for (int m = 0; m < FM; ++m)
        #pragma unroll
        for (int n = 0; n < FN; ++n) {
            const int col = ocol0 + n * 16;
            const float bv = bias[col];
            #pragma unroll
            for (int r = 0; r < 4; ++r)
                C[(size_t)(orow + m * 16 + r) * N + col] = acc[m][n][r] + bv;
        }
}

// Windowed attention. qkv f32 [B*S, 1536]; writes Y as bf16 [B*S, 512].
// 256 threads: thread t -> (q = t>>3, dg = t&7); O[q][dg*8 .. +8).
__global__ __launch_bounds__(256)
void attn2(const float* __restrict__ qkv, const int* __restrict__ pad,
           unsigned short* __restrict__ Yb) {
    const int bh = blockIdx.y, b = bh >> 3, h = bh & 7;
    const int i0 = blockIdx.x * QT, kb = i0 - HALF;
    const int t = threadIdx.x;

    __shared__ float Sc[QT][KW + 1];   // +1: dodge 32-way write conflicts
    __shared__ float KV[64][68];       // 68: row stride not = 0 mod 128B
    __shared__ int kvalid[KW];

    for (int idx = t; idx < KW; idx += 256) {
        const int j = kb + idx;
        kvalid[idx] = (j >= 0 && j < SEQ) ? pad[b * SEQ + j] : 0;
    }

    const int q = t >> 3, dg = t & 7;
    const int i = i0 + q;
    const size_t rowq = (size_t)(b * SEQ + i);
    const int pq = pad[b * SEQ + i];
    float4 Qa, Qb;
    {
        const float* qp = &qkv[rowq * 1536 + h * 192 + dg * 8];
        Qa = ((const float4*)qp)[0];
        Qb = ((const float4*)qp)[1];
    }
    const int sjj = t >> 2, sds = (t & 3) * 16;

    // ---- scores ----
    for (int c = 0; c < 5; ++c) {
        const int base = c * 64;
        const int nk = (KW - base >= 64) ? 64 : (KW - base);
        const int j = kb + base + sjj;
        if (sjj < nk && j >= 0 && j < SEQ) {
            const float* kp = &qkv[(size_t)(b * SEQ + j) * 1536 + h * 192 + DH + sds];
            float4* dst = (float4*)&KV[sjj][sds];
            dst[0] = ((const float4*)kp)[0];
            dst[1] = ((const float4*)kp)[1];
            dst[2] = ((const float4*)kp)[2];
            dst[3] = ((const float4*)kp)[3];
        }
        __syncthreads();
        for (int jj = 0; jj < nk; ++jj) {
            const float4 k0 = *(const float4*)&KV[jj][dg * 8];
            const float4 k1 = *(const float4*)&KV[jj][dg * 8 + 4];
            float p = Qa.x * k0.x + Qa.y * k0.y + Qa.z * k0.z + Qa.w * k0.w
                    + Qb.x * k1.x + Qb.y * k1.y + Qb.z * k1.z + Qb.w * k1.w;
            p += __shfl_xor(p, 1);
            p += __shfl_xor(p, 2);
            p += __shfl_xor(p, 4);
            const int jl = base + jj;
            if (dg == (jj & 7)) {
                const bool ok = pq && kvalid[jl] && (jl >= q) && (jl <= q + 2 * HALF);
                Sc[q][jl] = ok ? p * 0.125f : -1e30f;
            }
        }
        __syncthreads();
    }

    // ---- softmax: one wave per row ----
    const int wv = t >> 6, lane = t & 63;
    for (int r = wv; r < QT; r += 4) {
        const int pr = pad[b * SEQ + i0 + r];
        if (!pr) {
            for (int jl = lane; jl < KW; jl += 64) Sc[r][jl] = 0.f;
            continue;
        }
        float m = -1e30f;
        for (int jl = lane; jl < KW; jl += 64) m = fmaxf(m, Sc[r][jl]);
        #pragma unroll
        for (int off = 32; off; off >>= 1) m = fmaxf(m, __shfl_xor(m, off));
        float s = 0.f;
        for (int jl = lane; jl < KW; jl += 64) {
            float e = __expf(Sc[r][jl] - m);
            Sc[r][jl] = e;
            s += e;
        }
        #pragma unroll
        for (int off = 32; off; off >>= 1) s += __shfl_xor(s, off);
        const float inv = 1.f / s;
        for (int jl = lane; jl < KW; jl += 64) Sc[r][jl] *= inv;
    }
    __syncthreads();

    // ---- PV ----
    float O[8] = {0.f, 0.f, 0.f, 0.f, 0.f, 0.f, 0.f, 0.f};
    for (int c = 0; c < 5; ++c) {
        const int base = c * 64;
        const int nk = (KW - base >= 64) ? 64 : (KW - base);
        const int j = kb + base + sjj;
        if (sjj < nk && j >= 0 && j < SEQ) {
            const float* vp = &qkv[(size_t)(b * SEQ + j) * 1536 + h * 192 + 2 * DH + sds];
            float4* dst = (float4*)&KV[sjj][sds];
            dst[0] = ((const float4*)vp)[0];
            dst[1] = ((const float4*)vp)[1];
            dst[2] = ((const float4*)vp)[2];
            dst[3] = ((const float4*)vp)[3];
        }
        __syncthreads();
        for (int jj = 0; jj < nk; ++jj) {
            const float pv = Sc[q][base + jj];
            const float4 v0 = *(const float4*)&KV[jj][dg * 8];
            const float4 v1 = *(const float4*)&KV[jj][dg * 8 + 4];
            O[0] += pv * v0.x; O[1] += pv * v0.y; O[2] += pv * v0.z; O[3] += pv * v0.w;
            O[4] += pv * v1.x; O[5] += pv * v1.y; O[6] += pv * v1.z; O[7] += pv * v1.w;
        }
        __syncthreads();
    }

    unsigned short* yp = &Yb[rowq * EMB + h * DH + dg * 8];
    ((ushort4*)yp)[0] = make_ushort4(f2bf(O[0]), f2bf(O[1]), f2bf(O[2]), f2bf(O[3]));
    ((ushort4*)yp)[1] = make_ushort4(f2bf(O[4]), f2bf(O[5]), f2bf(O[6]), f2bf(O[7]));
}

extern "C" void kernel_launch(void* const* d_in, const int* in_sizes, int n_in,
                              void* d_out, int out_size, void* d_ws, size_t ws_size,
                              hipStream_t stream) {
    const float* x    = (const float*)d_in[0];
    const int*   pad  = (const int*)d_in[1];
    const float* Wqkv = (const float*)d_in[2];
    const float* bqkv = (const float*)d_in[3];
    const float* Wo   = (const float*)d_in[4];
    const float* bo   = (const float*)d_in[5];
    float* out = (float*)d_out;

    const int BS = 2 * SEQ;                       // 4096 rows
    float* qkv = (float*)d_ws;                    // [4096,1536] f32 = 25.2 MB
    char* p = (char*)d_ws + (size_t)BS * 1536 * 4;
    unsigned short* xb    = (unsigned short*)p;                    // 4 MB (reused as Yb)
    unsigned short* wqkvb = (unsigned short*)(p + 4194304);        // 1.5 MB
    unsigned short* wob   = (unsigned short*)(p + 4194304 + 1572864); // 0.5 MB
    unsigned short* Yb    = xb;                   // xb dead after gemm1

    dim3 blk(256);
    cvt_bf16<<<dim3((BS * DIM / 4) / 256), blk, 0, stream>>>(x, xb, BS * DIM / 4);
    cvt_bf16<<<dim3((3 * EMB * DIM / 4) / 256), blk, 0, stream>>>(Wqkv, wqkvb, 3 * EMB * DIM / 4);
    cvt_bf16<<<dim3((EMB * EMB / 4) / 256), blk, 0, stream>>>(Wo, wob, EMB * EMB / 4);

    // qkv = x @ Wqkv^T + bqkv   (4096 x 1536 x 512)
    gemm_bf16<128, 2, 2><<<dim3((3 * EMB) / 128, BS / 128), blk, 0, stream>>>(
        xb, wqkvb, bqkv, qkv, BS, 3 * EMB, DIM);
    // windowed attention -> Yb bf16 [4096, 512]
    attn2<<<dim3(SEQ / QT, 2 * NH), blk, 0, stream>>>(qkv, pad, Yb);
    // out = Y @ Wo^T + bo       (4096 x 512 x 512)
    gemm_bf16<64, 4, 1><<<dim3(EMB / 64, BS / 128), blk, 0, stream>>>(
        Yb, wob, bo, out, BS, EMB, DIM);
}

// Round 3
// 82.279 us; speedup vs baseline: 7.9081x; 2.7442x over previous
//
#include <hip/hip_runtime.h>

#define NH   8
#define SEQ  2048
#define DIM  512
#define EMB  512
#define DH   64
#define HALF 128
#define QT   32
#define KW   288          // 32 + 2*128
#define SCS  292          // Sc row stride (f32)
#define KS   68           // Q/K/V LDS row stride (bf16)

typedef __attribute__((ext_vector_type(8))) short short8;
typedef __attribute__((ext_vector_type(4))) float f32x4;

__device__ __forceinline__ unsigned short f2bf(float f) {
    unsigned int u = __float_as_uint(f);
    return (unsigned short)((u + 0x7fffu + ((u >> 16) & 1u)) >> 16);
}

__global__ __launch_bounds__(256)
void cvt_bf16(const float* __restrict__ in, unsigned short* __restrict__ out, int n4) {
    int i = blockIdx.x * blockDim.x + threadIdx.x;
    if (i >= n4) return;
    float4 v = ((const float4*)in)[i];
    ((ushort4*)out)[i] = make_ushort4(f2bf(v.x), f2bf(v.y), f2bf(v.z), f2bf(v.w));
}

// qkvh[b][h][t][s][d] bf16  <=  x[4096,512]bf16 @ Wqkv[1536,512]bf16^T + bqkv
__global__ __launch_bounds__(256)
void gemm_qkv(const unsigned short* __restrict__ A, const unsigned short* __restrict__ B,
              const float* __restrict__ bias, unsigned short* __restrict__ qkvh) {
    constexpr int BM = 128, BN = 128, BK = 32;
    const int K = DIM;
    __shared__ unsigned short As[BM * BK];
    __shared__ unsigned short Bs[BN * BK];
    const int t = threadIdx.x, lane = t & 63, wid = t >> 6;
    const int wr = wid >> 1, wc = wid & 1;
    const int bm = blockIdx.y * BM, bn = blockIdx.x * BN;

    f32x4 acc[4][4];
    #pragma unroll
    for (int m = 0; m < 4; ++m)
        #pragma unroll
        for (int n = 0; n < 4; ++n)
            acc[m][n] = (f32x4){0.f, 0.f, 0.f, 0.f};

    const int lr = lane & 15, lk = (lane >> 4) * 8;
    for (int kt = 0; kt < K; kt += BK) {
        #pragma unroll
        for (int off = 0; off < BM * BK; off += 2048) {
            const int e = off + t * 8, r = e >> 5, c = e & 31;
            *(short8*)&As[e] = *(const short8*)(A + (size_t)(bm + r) * K + kt + c);
        }
        #pragma unroll
        for (int off = 0; off < BN * BK; off += 2048) {
            const int e = off + t * 8, r = e >> 5, c = e & 31;
            *(short8*)&Bs[e] = *(const short8*)(B + (size_t)(bn + r) * K + kt + c);
        }
        __syncthreads();
        short8 af[4], bf[4];
        #pragma unroll
        for (int m = 0; m < 4; ++m) af[m] = *(const short8*)&As[(wr * 64 + m * 16 + lr) * BK + lk];
        #pragma unroll
        for (int n = 0; n < 4; ++n) bf[n] = *(const short8*)&Bs[(wc * 64 + n * 16 + lr) * BK + lk];
        #pragma unroll
        for (int m = 0; m < 4; ++m)
            #pragma unroll
            for (int n = 0; n < 4; ++n)
                acc[m][n] = __builtin_amdgcn_mfma_f32_16x16x32_bf16(af[m], bf[n], acc[m][n], 0, 0, 0);
        __syncthreads();
    }

    const int orow = bm + wr * 64 + (lane >> 4) * 4;
    const int oc0 = bn + wc * 64 + (lane & 15);
    #pragma unroll
    for (int n = 0; n < 4; ++n) {
        const int col = oc0 + n * 16;
        const int h = col / 192, rem = col - h * 192;
        const int ty = rem >> 6, d = rem & 63;
        const float bv = bias[col];
        #pragma unroll
        for (int m = 0; m < 4; ++m)
            #pragma unroll
            for (int r = 0; r < 4; ++r) {
                const int row = orow + m * 16 + r;
                const int bb = row >> 11, s = row & 2047;
                qkvh[((((size_t)bb * NH + h) * 3 + ty) * SEQ + s) * DH + d] =
                    f2bf(acc[m][n][r] + bv);
            }
    }
}

// out[M,N]f32 = A[M,K]bf16 @ B[N,K]bf16^T + bias
template<int BN, int WR, int WC>
__global__ __launch_bounds__(256)
void gemm_bf16(const unsigned short* __restrict__ A, const unsigned short* __restrict__ B,
               const float* __restrict__ bias, float* __restrict__ C,
               int M, int N, int K) {
    constexpr int BM = 128, BK = 32;
    constexpr int WM = BM / WR, WN = BN / WC;
    constexpr int FM = WM / 16, FN = WN / 16;
    __shared__ unsigned short As[BM * BK];
    __shared__ unsigned short Bs[BN * BK];
    const int t = threadIdx.x, lane = t & 63, wid = t >> 6;
    const int wr = wid / WC, wc = wid % WC;
    const int bm = blockIdx.y * BM, bn = blockIdx.x * BN;

    f32x4 acc[FM][FN];
    #pragma unroll
    for (int m = 0; m < FM; ++m)
        #pragma unroll
        for (int n = 0; n < FN; ++n)
            acc[m][n] = (f32x4){0.f, 0.f, 0.f, 0.f};

    const int lr = lane & 15, lk = (lane >> 4) * 8;
    for (int kt = 0; kt < K; kt += BK) {
        #pragma unroll
        for (int off = 0; off < BM * BK; off += 2048) {
            const int e = off + t * 8, r = e >> 5, c = e & 31;
            *(short8*)&As[e] = *(const short8*)(A + (size_t)(bm + r) * K + kt + c);
        }
        #pragma unroll
        for (int off = 0; off < BN * BK; off += 2048) {
            const int e = off + t * 8, r = e >> 5, c = e & 31;
            *(short8*)&Bs[e] = *(const short8*)(B + (size_t)(bn + r) * K + kt + c);
        }
        __syncthreads();
        short8 af[FM], bf[FN];
        #pragma unroll
        for (int m = 0; m < FM; ++m) af[m] = *(const short8*)&As[(wr * WM + m * 16 + lr) * BK + lk];
        #pragma unroll
        for (int n = 0; n < FN; ++n) bf[n] = *(const short8*)&Bs[(wc * WN + n * 16 + lr) * BK + lk];
        #pragma unroll
        for (int m = 0; m < FM; ++m)
            #pragma unroll
            for (int n = 0; n < FN; ++n)
                acc[m][n] = __builtin_amdgcn_mfma_f32_16x16x32_bf16(af[m], bf[n], acc[m][n], 0, 0, 0);
        __syncthreads();
    }

    const int orow = bm + wr * WM + (lane >> 4) * 4;
    const int oc0 = bn + wc * WN + (lane & 15);
    #pragma unroll
    for (int m = 0; m < FM; ++m)
        #pragma unroll
        for (int n = 0; n < FN; ++n) {
            const int col = oc0 + n * 16;
            const float bv = bias[col];
            #pragma unroll
            for (int r = 0; r < 4; ++r)
                C[(size_t)(orow + m * 16 + r) * N + col] = acc[m][n][r] + bv;
        }
}

// MFMA windowed attention. One block = (b,h, 32-query tile), 4 waves.
__global__ __launch_bounds__(256)
void attn_mfma(const unsigned short* __restrict__ qkvh, const int* __restrict__ pad,
               unsigned short* __restrict__ Yb) {
    const int bh = blockIdx.y, b = bh >> 3, h = bh & 7;
    const int i0 = blockIdx.x * QT, kb = i0 - HALF;
    const int t = threadIdx.x, lane = t & 63, w = t >> 6;

    __shared__ unsigned short Qs[QT * KS];
    __shared__ unsigned short KVs[64 * KS];
    __shared__ float Sc[QT * SCS];
    __shared__ int kvalid[KW];

    const unsigned short* Qg = qkvh + ((size_t)bh * 3 + 0) * SEQ * DH;
    const unsigned short* Kg = qkvh + ((size_t)bh * 3 + 1) * SEQ * DH;
    const unsigned short* Vg = qkvh + ((size_t)bh * 3 + 2) * SEQ * DH;

    for (int idx = t; idx < KW; idx += 256) {
        const int j = kb + idx;
        kvalid[idx] = (j >= 0 && j < SEQ) ? pad[b * SEQ + j] : 0;
    }
    {   // Q tile: 32x64, one short8 per thread
        const int r = t >> 3, c8 = (t & 7) * 8;
        *(short8*)&Qs[r * KS + c8] = *(const short8*)&Qg[(size_t)(i0 + r) * DH + c8];
    }
    __syncthreads();

    const int lr = lane & 15, lg = lane >> 4;
    short8 qf[2][2];
    #pragma unroll
    for (int m = 0; m < 2; ++m)
        #pragma unroll
        for (int kk = 0; kk < 2; ++kk)
            qf[m][kk] = *(const short8*)&Qs[(m * 16 + lr) * KS + kk * 32 + lg * 8];

    const int srow = t >> 2, scol = (t & 3) * 16;

    // ---- scores ----
    for (int c = 0; c < 5; ++c) {
        const int nc = (c < 4) ? 64 : 32;
        if (srow < nc) {
            const int j = kb + c * 64 + srow;
            if (j >= 0 && j < SEQ) {
                *(short8*)&KVs[srow * KS + scol]     = *(const short8*)&Kg[(size_t)j * DH + scol];
                *(short8*)&KVs[srow * KS + scol + 8] = *(const short8*)&Kg[(size_t)j * DH + scol + 8];
            } else {
                short8 z = {};
                *(short8*)&KVs[srow * KS + scol] = z;
                *(short8*)&KVs[srow * KS + scol + 8] = z;
            }
        }
        __syncthreads();
        const int k0 = w * 16;
        if (k0 < nc) {
            f32x4 a0 = (f32x4){0.f,0.f,0.f,0.f}, a1 = (f32x4){0.f,0.f,0.f,0.f};
            #pragma unroll
            for (int kk = 0; kk < 2; ++kk) {
                const short8 bfr = *(const short8*)&KVs[(k0 + lr) * KS + kk * 32 + lg * 8];
                a0 = __builtin_amdgcn_mfma_f32_16x16x32_bf16(qf[0][kk], bfr, a0, 0, 0, 0);
                a1 = __builtin_amdgcn_mfma_f32_16x16x32_bf16(qf[1][kk], bfr, a1, 0, 0, 0);
            }
            const int jl = c * 64 + k0 + lr;
            const int kv = kvalid[jl];
            #pragma unroll
            for (int r = 0; r < 4; ++r) {
                const int q0 = lg * 4 + r, q1 = 16 + q0;
                const bool ok0 = kv && (jl >= q0) && (jl <= q0 + 2 * HALF);
                const bool ok1 = kv && (jl >= q1) && (jl <= q1 + 2 * HALF);
                Sc[q0 * SCS + jl] = ok0 ? a0[r] * 0.125f : -1e30f;
                Sc[q1 * SCS + jl] = ok1 ? a1[r] * 0.125f : -1e30f;
            }
        }
        __syncthreads();
    }

    // ---- softmax: wave per row ----
    for (int r = w; r < QT; r += 4) {
        float* row = &Sc[r * SCS];
        if (!pad[b * SEQ + i0 + r]) {
            for (int jl = lane; jl < KW; jl += 64) row[jl] = 0.f;
            continue;
        }
        float mx = -1e30f;
        for (int jl = lane; jl < KW; jl += 64) mx = fmaxf(mx, row[jl]);
        #pragma unroll
        for (int off = 32; off; off >>= 1) mx = fmaxf(mx, __shfl_xor(mx, off));
        float s = 0.f;
        for (int jl = lane; jl < KW; jl += 64) {
            const float e = __expf(row[jl] - mx);
            row[jl] = e;
            s += e;
        }
        #pragma unroll
        for (int off = 32; off; off >>= 1) s += __shfl_xor(s, off);
        const float inv = 1.f / s;
        for (int jl = lane; jl < KW; jl += 64) row[jl] *= inv;
    }
    __syncthreads();

    // ---- PV ----
    f32x4 o0 = (f32x4){0.f,0.f,0.f,0.f}, o1 = (f32x4){0.f,0.f,0.f,0.f};
    const int d0 = w * 16 + lr;
    for (int c = 0; c < 5; ++c) {
        const int nc = (c < 4) ? 64 : 32;
        if (srow < nc) {
            const int j = kb + c * 64 + srow;
            if (j >= 0 && j < SEQ) {
                *(short8*)&KVs[srow * KS + scol]     = *(const short8*)&Vg[(size_t)j * DH + scol];
                *(short8*)&KVs[srow * KS + scol + 8] = *(const short8*)&Vg[(size_t)j * DH + scol + 8];
            } else {
                short8 z = {};
                *(short8*)&KVs[srow * KS + scol] = z;
                *(short8*)&KVs[srow * KS + scol + 8] = z;
            }
        }
        __syncthreads();
        const int nkk = nc >> 5;
        for (int kk = 0; kk < nkk; ++kk) {
            short8 vf;
            #pragma unroll
            for (int j_ = 0; j_ < 8; ++j_)
                vf[j_] = (short)KVs[(kk * 32 + lg * 8 + j_) * KS + d0];
            const float* p0 = &Sc[lr * SCS + c * 64 + kk * 32 + lg * 8];
            const float* p1 = &Sc[(16 + lr) * SCS + c * 64 + kk * 32 + lg * 8];
            short8 pf0, pf1;
            #pragma unroll
            for (int j_ = 0; j_ < 8; ++j_) {
                pf0[j_] = (short)f2bf(p0[j_]);
                pf1[j_] = (short)f2bf(p1[j_]);
            }
            o0 = __builtin_amdgcn_mfma_f32_16x16x32_bf16(pf0, vf, o0, 0, 0, 0);
            o1 = __builtin_amdgcn_mfma_f32_16x16x32_bf16(pf1, vf, o1, 0, 0, 0);
        }
        __syncthreads();
    }
    #pragma unroll
    for (int r = 0; r < 4; ++r) {
        Yb[(size_t)(b * SEQ + i0 + lg * 4 + r) * EMB + h * DH + d0]      = f2bf(o0[r]);
        Yb[(size_t)(b * SEQ + i0 + 16 + lg * 4 + r) * EMB + h * DH + d0] = f2bf(o1[r]);
    }
}

extern "C" void kernel_launch(void* const* d_in, const int* in_sizes, int n_in,
                              void* d_out, int out_size, void* d_ws, size_t ws_size,
                              hipStream_t stream) {
    const float* x    = (const float*)d_in[0];
    const int*   pad  = (const int*)d_in[1];
    const float* Wqkv = (const float*)d_in[2];
    const float* bqkv = (const float*)d_in[3];
    const float* Wo   = (const float*)d_in[4];
    const float* bo   = (const float*)d_in[5];
    float* out = (float*)d_out;

    const int BS = 2 * SEQ;   // 4096
    char* p = (char*)d_ws;
    unsigned short* qkvh = (unsigned short*)p;                       // 12.6 MB
    unsigned short* xb   = (unsigned short*)(p + 12582912);          // 4 MB
    unsigned short* wqkvb= (unsigned short*)(p + 12582912 + 4194304);// 1.5 MB
    unsigned short* wob  = (unsigned short*)(p + 12582912 + 4194304 + 1572864); // 0.5 MB
    unsigned short* Yb   = xb;   // xb dead after gemm_qkv

    dim3 blk(256);
    cvt_bf16<<<dim3((BS * DIM / 4) / 256), blk, 0, stream>>>(x, xb, BS * DIM / 4);
    cvt_bf16<<<dim3((3 * EMB * DIM / 4) / 256), blk, 0, stream>>>(Wqkv, wqkvb, 3 * EMB * DIM / 4);
    cvt_bf16<<<dim3((EMB * EMB / 4) / 256), blk, 0, stream>>>(Wo, wob, EMB * EMB / 4);

    gemm_qkv<<<dim3(12, 32), blk, 0, stream>>>(xb, wqkvb, bqkv, qkvh);
    attn_mfma<<<dim3(SEQ / QT, 2 * NH), blk, 0, stream>>>(qkvh, pad, Yb);
    gemm_bf16<64, 4, 1><<<dim3(EMB / 64, BS / 128), blk, 0, stream>>>(
        Yb, wob, bo, out, BS, EMB, DIM);
}

// Round 4
// 78.403 us; speedup vs baseline: 8.2990x; 1.0494x over previous
//
#include <hip/hip_runtime.h>

#define NH   8
#define SEQ  2048
#define DIM  512
#define EMB  512
#define DH   64
#define HALF 128
#define QT   32
#define KW   288          // 32 + 2*128
#define SCS  292          // Sc row stride (f32)
#define QKS  72           // Q/K/V LDS row stride (bf16, 144B = 16B-aligned)
#define PBS  296          // Pb row stride (bf16, 592B = 16B-aligned)

typedef __attribute__((ext_vector_type(8))) short short8;
typedef __attribute__((ext_vector_type(4))) float f32x4;

__device__ __forceinline__ unsigned short f2bf(float f) {
    unsigned int u = __float_as_uint(f);
    return (unsigned short)((u + 0x7fffu + ((u >> 16) & 1u)) >> 16);
}

__device__ __forceinline__ void gload_lds16(const void* g, void* l) {
    __builtin_amdgcn_global_load_lds((__attribute__((address_space(1))) void*)g,
                                     (__attribute__((address_space(3))) void*)l,
                                     16, 0, 0);
}

// one kernel converts x, Wqkv, Wo  ->  contiguous bf16 region
__global__ __launch_bounds__(256)
void cvt_all(const float* __restrict__ x, const float* __restrict__ wqkv,
             const float* __restrict__ wo, unsigned short* __restrict__ out) {
    const int i = blockIdx.x * 256 + threadIdx.x;   // float4 index, grid exact
    const float* src;
    int base;
    if (i < 524288)      { src = x;    base = 0; }
    else if (i < 720896) { src = wqkv; base = 524288; }
    else                 { src = wo;   base = 720896; }
    float4 v = ((const float4*)src)[i - base];
    ((ushort4*)out)[i] = make_ushort4(f2bf(v.x), f2bf(v.y), f2bf(v.z), f2bf(v.w));
}

// qkvh[b][h][t][s][d] bf16  <=  x[4096,512]bf16 @ Wqkv[1536,512]bf16^T + bqkv
__global__ __launch_bounds__(256)
void gemm_qkv(const unsigned short* __restrict__ A, const unsigned short* __restrict__ B,
              const float* __restrict__ bias, unsigned short* __restrict__ qkvh) {
    constexpr int BM = 128, BN = 128, BK = 32;
    const int K = DIM;
    __shared__ unsigned short As[BM * BK];
    __shared__ unsigned short Bs[BN * BK];
    const int t = threadIdx.x, lane = t & 63, wid = t >> 6;
    const int wr = wid >> 1, wc = wid & 1;
    const int bm = blockIdx.y * BM, bn = blockIdx.x * BN;

    f32x4 acc[4][4];
    #pragma unroll
    for (int m = 0; m < 4; ++m)
        #pragma unroll
        for (int n = 0; n < 4; ++n)
            acc[m][n] = (f32x4){0.f, 0.f, 0.f, 0.f};

    const int lr = lane & 15, lk = (lane >> 4) * 8;
    for (int kt = 0; kt < K; kt += BK) {
        #pragma unroll
        for (int off = 0; off < BM * BK; off += 2048) {
            const int e = off + t * 8, r = e >> 5, c = e & 31;
            gload_lds16(A + (size_t)(bm + r) * K + kt + c, &As[e]);
        }
        #pragma unroll
        for (int off = 0; off < BN * BK; off += 2048) {
            const int e = off + t * 8, r = e >> 5, c = e & 31;
            gload_lds16(B + (size_t)(bn + r) * K + kt + c, &Bs[e]);
        }
        __syncthreads();
        short8 af[4], bf[4];
        #pragma unroll
        for (int m = 0; m < 4; ++m) af[m] = *(const short8*)&As[(wr * 64 + m * 16 + lr) * BK + lk];
        #pragma unroll
        for (int n = 0; n < 4; ++n) bf[n] = *(const short8*)&Bs[(wc * 64 + n * 16 + lr) * BK + lk];
        #pragma unroll
        for (int m = 0; m < 4; ++m)
            #pragma unroll
            for (int n = 0; n < 4; ++n)
                acc[m][n] = __builtin_amdgcn_mfma_f32_16x16x32_bf16(af[m], bf[n], acc[m][n], 0, 0, 0);
        __syncthreads();
    }

    const int orow = bm + wr * 64 + (lane >> 4) * 4;
    const int oc0 = bn + wc * 64 + (lane & 15);
    #pragma unroll
    for (int n = 0; n < 4; ++n) {
        const int col = oc0 + n * 16;
        const int h = col / 192, rem = col - h * 192;
        const int ty = rem >> 6, d = rem & 63;
        const float bv = bias[col];
        #pragma unroll
        for (int m = 0; m < 4; ++m)
            #pragma unroll
            for (int r = 0; r < 4; ++r) {
                const int row = orow + m * 16 + r;
                const int bb = row >> 11, s = row & 2047;
                qkvh[((((size_t)bb * NH + h) * 3 + ty) * SEQ + s) * DH + d] =
                    f2bf(acc[m][n][r] + bv);
            }
    }
}

// vT[bh][d][s] <- qkvh v-plane transpose (64x64 LDS tiles, stride 66 u32-safe)
__global__ __launch_bounds__(256)
void vtrans(const unsigned short* __restrict__ qkvh, unsigned short* __restrict__ vT) {
    const int bh = blockIdx.y, s0 = blockIdx.x * 64;
    const unsigned short* Vg = qkvh + ((size_t)bh * 3 + 2) * SEQ * DH;
    unsigned short* vTg = vT + (size_t)bh * DH * SEQ;
    __shared__ unsigned short T[64 * 66];
    const int t = threadIdx.x;
    {
        const int s = t >> 2, part = t & 3;
        short8 v0 = *(const short8*)&Vg[(size_t)(s0 + s) * DH + part * 16];
        short8 v1 = *(const short8*)&Vg[(size_t)(s0 + s) * DH + part * 16 + 8];
        unsigned int* dst = (unsigned int*)&T[s * 66 + part * 16];
        const unsigned int* p0 = (const unsigned int*)&v0;
        const unsigned int* p1 = (const unsigned int*)&v1;
        dst[0] = p0[0]; dst[1] = p0[1]; dst[2] = p0[2]; dst[3] = p0[3];
        dst[4] = p1[0]; dst[5] = p1[1]; dst[6] = p1[2]; dst[7] = p1[3];
    }
    __syncthreads();
    {
        const int d = t >> 2, part = t & 3;
        alignas(16) unsigned short tmp[16];
        #pragma unroll
        for (int k = 0; k < 16; ++k) tmp[k] = T[(part * 16 + k) * 66 + d];
        *(short8*)&vTg[(size_t)d * SEQ + s0 + part * 16]     = *(short8*)&tmp[0];
        *(short8*)&vTg[(size_t)d * SEQ + s0 + part * 16 + 8] = *(short8*)&tmp[8];
    }
}

// out[M,N]f32 = A[M,K]bf16 @ B[N,K]bf16^T + bias
template<int BN, int WR, int WC>
__global__ __launch_bounds__(256)
void gemm_bf16(const unsigned short* __restrict__ A, const unsigned short* __restrict__ B,
               const float* __restrict__ bias, float* __restrict__ C,
               int M, int N, int K) {
    constexpr int BM = 128, BK = 32;
    constexpr int WM = BM / WR, WN = BN / WC;
    constexpr int FM = WM / 16, FN = WN / 16;
    __shared__ unsigned short As[BM * BK];
    __shared__ unsigned short Bs[BN * BK];
    const int t = threadIdx.x, lane = t & 63, wid = t >> 6;
    const int wr = wid / WC, wc = wid % WC;
    const int bm = blockIdx.y * BM, bn = blockIdx.x * BN;

    f32x4 acc[FM][FN];
    #pragma unroll
    for (int m = 0; m < FM; ++m)
        #pragma unroll
        for (int n = 0; n < FN; ++n)
            acc[m][n] = (f32x4){0.f, 0.f, 0.f, 0.f};

    const int lr = lane & 15, lk = (lane >> 4) * 8;
    for (int kt = 0; kt < K; kt += BK) {
        #pragma unroll
        for (int off = 0; off < BM * BK; off += 2048) {
            const int e = off + t * 8, r = e >> 5, c = e & 31;
            gload_lds16(A + (size_t)(bm + r) * K + kt + c, &As[e]);
        }
        #pragma unroll
        for (int off = 0; off < BN * BK; off += 2048) {
            const int e = off + t * 8, r = e >> 5, c = e & 31;
            gload_lds16(B + (size_t)(bn + r) * K + kt + c, &Bs[e]);
        }
        __syncthreads();
        short8 af[FM], bf[FN];
        #pragma unroll
        for (int m = 0; m < FM; ++m) af[m] = *(const short8*)&As[(wr * WM + m * 16 + lr) * BK + lk];
        #pragma unroll
        for (int n = 0; n < FN; ++n) bf[n] = *(const short8*)&Bs[(wc * WN + n * 16 + lr) * BK + lk];
        #pragma unroll
        for (int m = 0; m < FM; ++m)
            #pragma unroll
            for (int n = 0; n < FN; ++n)
                acc[m][n] = __builtin_amdgcn_mfma_f32_16x16x32_bf16(af[m], bf[n], acc[m][n], 0, 0, 0);
        __syncthreads();
    }

    const int orow = bm + wr * WM + (lane >> 4) * 4;
    const int oc0 = bn + wc * WN + (lane & 15);
    #pragma unroll
    for (int m = 0; m < FM; ++m)
        #pragma unroll
        for (int n = 0; n < FN; ++n) {
            const int col = oc0 + n * 16;
            const float bv = bias[col];
            #pragma unroll
            for (int r = 0; r < 4; ++r)
                C[(size_t)(orow + m * 16 + r) * N + col] = acc[m][n][r] + bv;
        }
}

// MFMA windowed attention. One block = (b,h, 32-query tile), 4 waves.
__global__ __launch_bounds__(256)
void attn_mfma(const unsigned short* __restrict__ qkvh,
               const unsigned short* __restrict__ vT,
               const int* __restrict__ pad,
               unsigned short* __restrict__ Yb) {
    const int bh = blockIdx.y, b = bh >> 3, h = bh & 7;
    const int i0 = blockIdx.x * QT, kb = i0 - HALF;
    const int t = threadIdx.x, lane = t & 63, w = t >> 6;

    __shared__ unsigned short Qs[QT * QKS];
    __shared__ unsigned short KVs[64 * QKS];
    __shared__ float Sc[QT * SCS];
    __shared__ unsigned short Pb[QT * PBS];
    __shared__ int kvalid[KW];

    const unsigned short* Qg = qkvh + ((size_t)bh * 3 + 0) * SEQ * DH;
    const unsigned short* Kg = qkvh + ((size_t)bh * 3 + 1) * SEQ * DH;
    const unsigned short* vTg = vT + (size_t)bh * DH * SEQ;

    for (int idx = t; idx < KW; idx += 256) {
        const int j = kb + idx;
        kvalid[idx] = (j >= 0 && j < SEQ) ? pad[b * SEQ + j] : 0;
    }
    {   // Q tile: 32x64
        const int r = t >> 3, c8 = (t & 7) * 8;
        *(short8*)&Qs[r * QKS + c8] = *(const short8*)&Qg[(size_t)(i0 + r) * DH + c8];
    }
    __syncthreads();

    const int lr = lane & 15, lg = lane >> 4;
    short8 qf[2][2];
    #pragma unroll
    for (int m = 0; m < 2; ++m)
        #pragma unroll
        for (int kk = 0; kk < 2; ++kk)
            qf[m][kk] = *(const short8*)&Qs[(m * 16 + lr) * QKS + kk * 32 + lg * 8];

    const int srow = t >> 2, spart = t & 3, scol = (t & 3) * 16;

    // ---- scores ----
    for (int c = 0; c < 5; ++c) {
        const int nc = (c < 4) ? 64 : 32;
        if (srow < nc) {
            const int j = kb + c * 64 + srow;
            if (j >= 0 && j < SEQ) {
                *(short8*)&KVs[srow * QKS + scol]     = *(const short8*)&Kg[(size_t)j * DH + scol];
                *(short8*)&KVs[srow * QKS + scol + 8] = *(const short8*)&Kg[(size_t)j * DH + scol + 8];
            } else {
                short8 z = {};
                *(short8*)&KVs[srow * QKS + scol] = z;
                *(short8*)&KVs[srow * QKS + scol + 8] = z;
            }
        }
        __syncthreads();
        const int k0 = w * 16;
        if (k0 < nc) {
            f32x4 a0 = (f32x4){0.f,0.f,0.f,0.f}, a1 = (f32x4){0.f,0.f,0.f,0.f};
            #pragma unroll
            for (int kk = 0; kk < 2; ++kk) {
                const short8 bfr = *(const short8*)&KVs[(k0 + lr) * QKS + kk * 32 + lg * 8];
                a0 = __builtin_amdgcn_mfma_f32_16x16x32_bf16(qf[0][kk], bfr, a0, 0, 0, 0);
                a1 = __builtin_amdgcn_mfma_f32_16x16x32_bf16(qf[1][kk], bfr, a1, 0, 0, 0);
            }
            const int jl = c * 64 + k0 + lr;
            const int kv = kvalid[jl];
            #pragma unroll
            for (int r = 0; r < 4; ++r) {
                const int q0 = lg * 4 + r, q1 = 16 + q0;
                const bool ok0 = kv && (jl >= q0) && (jl <= q0 + 2 * HALF);
                const bool ok1 = kv && (jl >= q1) && (jl <= q1 + 2 * HALF);
                Sc[q0 * SCS + jl] = ok0 ? a0[r] * 0.125f : -1e30f;
                Sc[q1 * SCS + jl] = ok1 ? a1[r] * 0.125f : -1e30f;
            }
        }
        __syncthreads();
    }

    // ---- softmax: wave per row; writes bf16 P-tile ----
    for (int r = w; r < QT; r += 4) {
        float* row = &Sc[r * SCS];
        unsigned short* prow = &Pb[r * PBS];
        if (!pad[b * SEQ + i0 + r]) {
            for (int jl = lane; jl < KW; jl += 64) prow[jl] = 0;
            continue;
        }
        float mx = -1e30f;
        for (int jl = lane; jl < KW; jl += 64) mx = fmaxf(mx, row[jl]);
        #pragma unroll
        for (int off = 32; off; off >>= 1) mx = fmaxf(mx, __shfl_xor(mx, off));
        float s = 0.f;
        for (int jl = lane; jl < KW; jl += 64) {
            const float e = __expf(row[jl] - mx);
            row[jl] = e;
            s += e;
        }
        #pragma unroll
        for (int off = 32; off; off >>= 1) s += __shfl_xor(s, off);
        const float inv = 1.f / s;
        for (int jl = lane; jl < KW; jl += 64) prow[jl] = f2bf(row[jl] * inv);
    }
    __syncthreads();

    // ---- PV: stage V^T chunk, contiguous b128 fragments ----
    f32x4 o0 = (f32x4){0.f,0.f,0.f,0.f}, o1 = (f32x4){0.f,0.f,0.f,0.f};
    for (int c = 0; c < 5; ++c) {
        const int nc = (c < 4) ? 64 : 32;
        if (spart * 16 < nc) {          // srow = d row (all 64), spart = 16-key chunk
            const int j0 = kb + c * 64 + spart * 16;
            const unsigned short* src = vTg + (size_t)srow * SEQ;
            short8 va, vb;
            if (j0 >= 0 && j0 + 16 <= SEQ) {
                va = *(const short8*)&src[j0];
                vb = *(const short8*)&src[j0 + 8];
            } else {
                #pragma unroll
                for (int k2 = 0; k2 < 8; ++k2) {
                    int ja = j0 + k2;     ja = ja < 0 ? 0 : (ja > SEQ - 1 ? SEQ - 1 : ja);
                    int jb = j0 + 8 + k2; jb = jb < 0 ? 0 : (jb > SEQ - 1 ? SEQ - 1 : jb);
                    va[k2] = (short)src[ja];   // P=0 there, value irrelevant (finite)
                    vb[k2] = (short)src[jb];
                }
            }
            *(short8*)&KVs[srow * QKS + scol]     = va;
            *(short8*)&KVs[srow * QKS + scol + 8] = vb;
        }
        __syncthreads();
        const int nkk = nc >> 5;
        for (int kk = 0; kk < nkk; ++kk) {
            const short8 vf  = *(const short8*)&KVs[(w * 16 + lr) * QKS + kk * 32 + lg * 8];
            const short8 pf0 = *(const short8*)&Pb[lr * PBS + c * 64 + kk * 32 + lg * 8];
            const short8 pf1 = *(const short8*)&Pb[(16 + lr) * PBS + c * 64 + kk * 32 + lg * 8];
            o0 = __builtin_amdgcn_mfma_f32_16x16x32_bf16(pf0, vf, o0, 0, 0, 0);
            o1 = __builtin_amdgcn_mfma_f32_16x16x32_bf16(pf1, vf, o1, 0, 0, 0);
        }
        __syncthreads();
    }

    const int d0 = w * 16 + lr;
    #pragma unroll
    for (int r = 0; r < 4; ++r) {
        Yb[(size_t)(b * SEQ + i0 + lg * 4 + r) * EMB + h * DH + d0]      = f2bf(o0[r]);
        Yb[(size_t)(b * SEQ + i0 + 16 + lg * 4 + r) * EMB + h * DH + d0] = f2bf(o1[r]);
    }
}

extern "C" void kernel_launch(void* const* d_in, const int* in_sizes, int n_in,
                              void* d_out, int out_size, void* d_ws, size_t ws_size,
                              hipStream_t stream) {
    const float* x    = (const float*)d_in[0];
    const int*   pad  = (const int*)d_in[1];
    const float* Wqkv = (const float*)d_in[2];
    const float* bqkv = (const float*)d_in[3];
    const float* Wo   = (const float*)d_in[4];
    const float* bo   = (const float*)d_in[5];
    float* out = (float*)d_out;

    const int BS = 2 * SEQ;   // 4096
    char* p = (char*)d_ws;
    unsigned short* qkvh  = (unsigned short*)p;                   // 12.6 MB
    unsigned short* vT    = (unsigned short*)(p + 12582912);      // 4 MB
    unsigned short* xb    = (unsigned short*)(p + 16777216);      // 4 MB (cvt region base)
    unsigned short* wqkvb = (unsigned short*)(p + 20971520);      // 1.5 MB
    unsigned short* wob   = (unsigned short*)(p + 22544384);      // 0.5 MB
    unsigned short* Yb    = xb;   // xb dead after gemm_qkv

    dim3 blk(256);
    cvt_all<<<dim3(3072), blk, 0, stream>>>(x, Wqkv, Wo, xb);
    gemm_qkv<<<dim3(12, 32), blk, 0, stream>>>(xb, wqkvb, bqkv, qkvh);
    vtrans<<<dim3(SEQ / 64, 2 * NH), blk, 0, stream>>>(qkvh, vT);
    attn_mfma<<<dim3(SEQ / QT, 2 * NH), blk, 0, stream>>>(qkvh, vT, pad, Yb);
    gemm_bf16<64, 4, 1><<<dim3(EMB / 64, BS / 128), blk, 0, stream>>>(
        Yb, wob, bo, out, BS, EMB, DIM);
}

// Round 5
// 63.972 us; speedup vs baseline: 10.1711x; 1.2256x over previous
//
#include <hip/hip_runtime.h>

#define NH   8
#define SEQ  2048
#define DIM  512
#define EMB  512
#define DH   64
#define HALF 128
#define QT   32
#define KW   288          // 32 + 2*128
#define SCS  292          // Sc row stride (f32); bytes/row = 1168 (16B-aligned)
#define QKS  72           // K/V LDS row stride (bf16, 144B)

typedef __attribute__((ext_vector_type(8))) short short8;
typedef __attribute__((ext_vector_type(4))) float f32x4;

__device__ __forceinline__ unsigned short f2bf(float f) {
    unsigned int u = __float_as_uint(f);
    return (unsigned short)((u + 0x7fffu + ((u >> 16) & 1u)) >> 16);
}

__device__ __forceinline__ void gload_lds16(const void* g, void* l) {
    __builtin_amdgcn_global_load_lds((__attribute__((address_space(1))) void*)g,
                                     (__attribute__((address_space(3))) void*)l,
                                     16, 0, 0);
}

// one kernel converts x, Wqkv, Wo -> contiguous bf16 region
__global__ __launch_bounds__(256)
void cvt_all(const float* __restrict__ x, const float* __restrict__ wqkv,
             const float* __restrict__ wo, unsigned short* __restrict__ out) {
    const int i = blockIdx.x * 256 + threadIdx.x;   // float4 index, grid exact
    const float* src;
    int base;
    if (i < 524288)      { src = x;    base = 0; }
    else if (i < 720896) { src = wqkv; base = 524288; }
    else                 { src = wo;   base = 720896; }
    float4 v = ((const float4*)src)[i - base];
    ((ushort4*)out)[i] = make_ushort4(f2bf(v.x), f2bf(v.y), f2bf(v.z), f2bf(v.w));
}

// qkv projection: 128x64 tiles, 768 blocks. Writes Q,K to qkvh[b][h][ty][s][d]
// and V directly transposed to vT[b][h][d][s].
__global__ __launch_bounds__(256)
void gemm_qkv(const unsigned short* __restrict__ A, const unsigned short* __restrict__ B,
              const float* __restrict__ bias, unsigned short* __restrict__ qkvh,
              unsigned short* __restrict__ vT) {
    constexpr int BM = 128, BN = 64, BK = 32;
    const int K = DIM;
    __shared__ unsigned short As[BM * BK];
    __shared__ unsigned short Bs[BN * BK];
    const int t = threadIdx.x, lane = t & 63, wid = t >> 6;
    const int wr = wid >> 1, wc = wid & 1;
    const int bm = blockIdx.y * BM, bn = blockIdx.x * BN;

    f32x4 acc[4][2];
    #pragma unroll
    for (int m = 0; m < 4; ++m)
        #pragma unroll
        for (int n = 0; n < 2; ++n)
            acc[m][n] = (f32x4){0.f, 0.f, 0.f, 0.f};

    const int lr = lane & 15, lg = lane >> 4, lk = lg * 8;
    for (int kt = 0; kt < K; kt += BK) {
        #pragma unroll
        for (int off = 0; off < BM * BK; off += 2048) {
            const int e = off + t * 8, r = e >> 5, c = e & 31;
            gload_lds16(A + (size_t)(bm + r) * K + kt + c, &As[e]);
        }
        {
            const int e = t * 8, r = e >> 5, c = e & 31;
            gload_lds16(B + (size_t)(bn + r) * K + kt + c, &Bs[e]);
        }
        __syncthreads();
        short8 af[4], bf[2];
        #pragma unroll
        for (int m = 0; m < 4; ++m) af[m] = *(const short8*)&As[(wr * 64 + m * 16 + lr) * BK + lk];
        #pragma unroll
        for (int n = 0; n < 2; ++n) bf[n] = *(const short8*)&Bs[(wc * 32 + n * 16 + lr) * BK + lk];
        #pragma unroll
        for (int m = 0; m < 4; ++m)
            #pragma unroll
            for (int n = 0; n < 2; ++n)
                acc[m][n] = __builtin_amdgcn_mfma_f32_16x16x32_bf16(af[m], bf[n], acc[m][n], 0, 0, 0);
        __syncthreads();
    }

    const int bb = bm >> 11;                  // batch (tile never straddles)
    const int sbase = (bm & 2047) + wr * 64 + lg * 4;
    const int oc0 = bn + wc * 32 + lr;
    #pragma unroll
    for (int n = 0; n < 2; ++n) {
        const int col = oc0 + n * 16;
        const int h = col / 192, rem = col - h * 192;
        const int ty = rem >> 6, d = rem & 63;
        const float bv = bias[col];
        if (ty == 2) {                        // V: packed transposed store
            unsigned short* vrow = vT + ((size_t)(bb * NH + h) * DH + d) * SEQ;
            #pragma unroll
            for (int m = 0; m < 4; ++m) {
                const int s0 = sbase + m * 16;
                ushort4 pk = make_ushort4(f2bf(acc[m][n][0] + bv), f2bf(acc[m][n][1] + bv),
                                          f2bf(acc[m][n][2] + bv), f2bf(acc[m][n][3] + bv));
                *(ushort4*)&vrow[s0] = pk;
            }
        } else {                              // Q,K: scatter
            unsigned short* plane = qkvh + (((size_t)(bb * NH + h) * 3 + ty) * SEQ) * DH + d;
            #pragma unroll
            for (int m = 0; m < 4; ++m)
                #pragma unroll
                for (int r = 0; r < 4; ++r)
                    plane[(size_t)(sbase + m * 16 + r) * DH] = f2bf(acc[m][n][r] + bv);
        }
    }
}

// out[M,N]f32 = A[M,K]bf16 @ B[N,K]bf16^T + bias
template<int BM, int BN, int WR, int WC>
__global__ __launch_bounds__(256)
void gemm_bf16(const unsigned short* __restrict__ A, const unsigned short* __restrict__ B,
               const float* __restrict__ bias, float* __restrict__ C,
               int M, int N, int K) {
    constexpr int BK = 32;
    constexpr int WM = BM / WR, WN = BN / WC;
    constexpr int FM = WM / 16, FN = WN / 16;
    __shared__ unsigned short As[BM * BK];
    __shared__ unsigned short Bs[BN * BK];
    const int t = threadIdx.x, lane = t & 63, wid = t >> 6;
    const int wr = wid / WC, wc = wid % WC;
    const int bm = blockIdx.y * BM, bn = blockIdx.x * BN;

    f32x4 acc[FM][FN];
    #pragma unroll
    for (int m = 0; m < FM; ++m)
        #pragma unroll
        for (int n = 0; n < FN; ++n)
            acc[m][n] = (f32x4){0.f, 0.f, 0.f, 0.f};

    const int lr = lane & 15, lk = (lane >> 4) * 8;
    for (int kt = 0; kt < K; kt += BK) {
        #pragma unroll
        for (int off = 0; off < BM * BK; off += 2048) {
            const int e = off + t * 8, r = e >> 5, c = e & 31;
            gload_lds16(A + (size_t)(bm + r) * K + kt + c, &As[e]);
        }
        #pragma unroll
        for (int off = 0; off < BN * BK; off += 2048) {
            const int e = off + t * 8, r = e >> 5, c = e & 31;
            gload_lds16(B + (size_t)(bn + r) * K + kt + c, &Bs[e]);
        }
        __syncthreads();
        short8 af[FM], bf[FN];
        #pragma unroll
        for (int m = 0; m < FM; ++m) af[m] = *(const short8*)&As[(wr * WM + m * 16 + lr) * BK + lk];
        #pragma unroll
        for (int n = 0; n < FN; ++n) bf[n] = *(const short8*)&Bs[(wc * WN + n * 16 + lr) * BK + lk];
        #pragma unroll
        for (int m = 0; m < FM; ++m)
            #pragma unroll
            for (int n = 0; n < FN; ++n)
                acc[m][n] = __builtin_amdgcn_mfma_f32_16x16x32_bf16(af[m], bf[n], acc[m][n], 0, 0, 0);
        __syncthreads();
    }

    const int orow = bm + wr * WM + (lane >> 4) * 4;
    const int oc0 = bn + wc * WN + (lane & 15);
    #pragma unroll
    for (int m = 0; m < FM; ++m)
        #pragma unroll
        for (int n = 0; n < FN; ++n) {
            const int col = oc0 + n * 16;
            const float bv = bias[col];
            #pragma unroll
            for (int r = 0; r < 4; ++r)
                C[(size_t)(orow + m * 16 + r) * N + col] = acc[m][n][r] + bv;
        }
}

// MFMA windowed attention. One block = (b,h, 32-query tile), 4 waves.
// Double-buffered chunk staging, one barrier per chunk; P written in-place
// over Sc (bf16 into the f32 slots' low bytes at u16 index jl).
__global__ __launch_bounds__(256)
void attn_mfma(const unsigned short* __restrict__ qkvh,
               const unsigned short* __restrict__ vT,
               const int* __restrict__ pad,
               unsigned short* __restrict__ Yb) {
    const int bh = blockIdx.y, b = bh >> 3, h = bh & 7;
    const int i0 = blockIdx.x * QT, kb = i0 - HALF;
    const int t = threadIdx.x, lane = t & 63, w = t >> 6;

    __shared__ unsigned short Qs[QT * QKS];
    __shared__ unsigned short KVs[2][64 * QKS];
    __shared__ float Sc[QT * SCS];
    __shared__ int kvalid[KW];

    const unsigned short* Qg = qkvh + ((size_t)bh * 3 + 0) * SEQ * DH;
    const unsigned short* Kg = qkvh + ((size_t)bh * 3 + 1) * SEQ * DH;
    const unsigned short* vTg = vT + (size_t)bh * DH * SEQ;

    for (int idx = t; idx < KW; idx += 256) {
        const int j = kb + idx;
        kvalid[idx] = (j >= 0 && j < SEQ) ? pad[b * SEQ + j] : 0;
    }
    {   // Q tile: 32x64
        const int r = t >> 3, c8 = (t & 7) * 8;
        *(short8*)&Qs[r * QKS + c8] = *(const short8*)&Qg[(size_t)(i0 + r) * DH + c8];
    }
    __syncthreads();

    const int lr = lane & 15, lg = lane >> 4;
    short8 qf[2][2];
    #pragma unroll
    for (int m = 0; m < 2; ++m)
        #pragma unroll
        for (int kk = 0; kk < 2; ++kk)
            qf[m][kk] = *(const short8*)&Qs[(m * 16 + lr) * QKS + kk * 32 + lg * 8];

    const int srow = t >> 2, spart = t & 3, scol = spart * 16;

    auto loadK = [&](int c, short8& va, short8& vb) {
        const int j = kb + c * 64 + srow;
        if (j >= 0 && j < SEQ) {
            va = *(const short8*)&Kg[(size_t)j * DH + scol];
            vb = *(const short8*)&Kg[(size_t)j * DH + scol + 8];
        } else {
            short8 z = {};
            va = z; vb = z;
        }
    };
    auto loadV = [&](int c, short8& va, short8& vb) {
        const int j0 = kb + c * 64 + scol;
        const unsigned short* src = vTg + (size_t)srow * SEQ;
        if (j0 >= 0 && j0 + 16 <= SEQ) {
            va = *(const short8*)&src[j0];
            vb = *(const short8*)&src[j0 + 8];
        } else {
            #pragma unroll
            for (int k2 = 0; k2 < 8; ++k2) {
                int ja = j0 + k2;     ja = ja < 0 ? 0 : (ja > SEQ - 1 ? SEQ - 1 : ja);
                int jb = j0 + 8 + k2; jb = jb < 0 ? 0 : (jb > SEQ - 1 ? SEQ - 1 : jb);
                va[k2] = (short)src[ja];
                vb[k2] = (short)src[jb];
            }
        }
    };

    short8 ra, rb;
    loadK(0, ra, rb);

    // ---- scores: 1 barrier per chunk, loads hidden under compute ----
    for (int c = 0; c < 5; ++c) {
        unsigned short* buf = &KVs[c & 1][0];
        *(short8*)&buf[srow * QKS + scol] = ra;
        *(short8*)&buf[srow * QKS + scol + 8] = rb;
        __syncthreads();
        if (c < 4) loadK(c + 1, ra, rb);
        const int nc = (c < 4) ? 64 : 32;
        const int k0 = w * 16;
        if (k0 < nc) {
            f32x4 a0 = (f32x4){0.f,0.f,0.f,0.f}, a1 = (f32x4){0.f,0.f,0.f,0.f};
            __builtin_amdgcn_s_setprio(1);
            #pragma unroll
            for (int kk = 0; kk < 2; ++kk) {
                const short8 bfr = *(const short8*)&buf[(k0 + lr) * QKS + kk * 32 + lg * 8];
                a0 = __builtin_amdgcn_mfma_f32_16x16x32_bf16(qf[0][kk], bfr, a0, 0, 0, 0);
                a1 = __builtin_amdgcn_mfma_f32_16x16x32_bf16(qf[1][kk], bfr, a1, 0, 0, 0);
            }
            __builtin_amdgcn_s_setprio(0);
            const int jl = c * 64 + k0 + lr;
            const int kv = kvalid[jl];
            #pragma unroll
            for (int r = 0; r < 4; ++r) {
                const int q0 = lg * 4 + r, q1 = 16 + q0;
                const bool ok0 = kv && (jl >= q0) && (jl <= q0 + 2 * HALF);
                const bool ok1 = kv && (jl >= q1) && (jl <= q1 + 2 * HALF);
                Sc[q0 * SCS + jl] = ok0 ? a0[r] * 0.125f : -1e30f;
                Sc[q1 * SCS + jl] = ok1 ? a1[r] * 0.125f : -1e30f;
            }
        }
    }

    loadV(0, ra, rb);          // V chunk-0 latency hides under softmax
    __syncthreads();

    // ---- softmax: wave per row; P (bf16) written in place over Sc ----
    for (int r = w; r < QT; r += 4) {
        float* row = &Sc[r * SCS];
        unsigned short* prow = (unsigned short*)row;
        if (!pad[b * SEQ + i0 + r]) {
            #pragma unroll
            for (int u = 0; u < 5; ++u) {
                const int jl = lane + 64 * u;
                if (jl < KW) prow[jl] = 0;
            }
            continue;
        }
        float mx = -1e30f;
        #pragma unroll
        for (int u = 0; u < 5; ++u) {
            const int jl = lane + 64 * u;
            if (jl < KW) mx = fmaxf(mx, row[jl]);
        }
        #pragma unroll
        for (int off = 32; off; off >>= 1) mx = fmaxf(mx, __shfl_xor(mx, off));
        float ev[5];
        float s = 0.f;
        #pragma unroll
        for (int u = 0; u < 5; ++u) {
            const int jl = lane + 64 * u;
            if (jl < KW) { ev[u] = __expf(row[jl] - mx); s += ev[u]; }
        }
        #pragma unroll
        for (int off = 32; off; off >>= 1) s += __shfl_xor(s, off);
        const float inv = 1.f / s;
        #pragma unroll
        for (int u = 0; u < 5; ++u) {
            const int jl = lane + 64 * u;
            if (jl < KW) prow[jl] = f2bf(ev[u] * inv);
        }
    }
    __syncthreads();

    // ---- PV: same 1-barrier double-buffered scheme ----
    f32x4 o0 = (f32x4){0.f,0.f,0.f,0.f}, o1 = (f32x4){0.f,0.f,0.f,0.f};
    const unsigned short* PbU = (const unsigned short*)Sc;
    for (int c = 0; c < 5; ++c) {
        unsigned short* buf = &KVs[c & 1][0];
        *(short8*)&buf[srow * QKS + scol] = ra;
        *(short8*)&buf[srow * QKS + scol + 8] = rb;
        __syncthreads();
        if (c < 4) loadV(c + 1, ra, rb);
        const int nkk = (c < 4) ? 2 : 1;
        __builtin_amdgcn_s_setprio(1);
        for (int kk = 0; kk < nkk; ++kk) {
            const short8 vf  = *(const short8*)&buf[(w * 16 + lr) * QKS + kk * 32 + lg * 8];
            const short8 pf0 = *(const short8*)&PbU[lr * (SCS * 2) + c * 64 + kk * 32 + lg * 8];
            const short8 pf1 = *(const short8*)&PbU[(16 + lr) * (SCS * 2) + c * 64 + kk * 32 + lg * 8];
            o0 = __builtin_amdgcn_mfma_f32_16x16x32_bf16(pf0, vf, o0, 0, 0, 0);
            o1 = __builtin_amdgcn_mfma_f32_16x16x32_bf16(pf1, vf, o1, 0, 0, 0);
        }
        __builtin_amdgcn_s_setprio(0);
    }

    const int d0 = w * 16 + lr;
    #pragma unroll
    for (int r = 0; r < 4; ++r) {
        Yb[(size_t)(b * SEQ + i0 + lg * 4 + r) * EMB + h * DH + d0]      = f2bf(o0[r]);
        Yb[(size_t)(b * SEQ + i0 + 16 + lg * 4 + r) * EMB + h * DH + d0] = f2bf(o1[r]);
    }
}

extern "C" void kernel_launch(void* const* d_in, const int* in_sizes, int n_in,
                              void* d_out, int out_size, void* d_ws, size_t ws_size,
                              hipStream_t stream) {
    const float* x    = (const float*)d_in[0];
    const int*   pad  = (const int*)d_in[1];
    const float* Wqkv = (const float*)d_in[2];
    const float* bqkv = (const float*)d_in[3];
    const float* Wo   = (const float*)d_in[4];
    const float* bo   = (const float*)d_in[5];
    float* out = (float*)d_out;

    const int BS = 2 * SEQ;   // 4096
    char* p = (char*)d_ws;
    unsigned short* qkvh  = (unsigned short*)p;                   // 12.6 MB (Q,K planes used)
    unsigned short* vT    = (unsigned short*)(p + 12582912);      // 4 MB
    unsigned short* xb    = (unsigned short*)(p + 16777216);      // 4 MB (cvt region base)
    unsigned short* wqkvb = (unsigned short*)(p + 20971520);      // 1.5 MB
    unsigned short* wob   = (unsigned short*)(p + 22544384);      // 0.5 MB
    unsigned short* Yb    = xb;   // xb dead after gemm_qkv

    dim3 blk(256);
    cvt_all<<<dim3(3072), blk, 0, stream>>>(x, Wqkv, Wo, xb);
    gemm_qkv<<<dim3(24, 32), blk, 0, stream>>>(xb, wqkvb, bqkv, qkvh, vT);
    attn_mfma<<<dim3(SEQ / QT, 2 * NH), blk, 0, stream>>>(qkvh, vT, pad, Yb);
    gemm_bf16<64, 64, 2, 2><<<dim3(EMB / 64, BS / 64), blk, 0, stream>>>(
        Yb, wob, bo, out, BS, EMB, DIM);
}

// Round 6
// 59.872 us; speedup vs baseline: 10.8677x; 1.0685x over previous
//
#include <hip/hip_runtime.h>

#define NH   8
#define SEQ  2048
#define DIM  512
#define EMB  512
#define DH   64
#define HALF 128
#define QT   16
#define KW   272          // QT + 2*HALF
#define SCS  276          // Sc row stride (f32); 1104B rows, 16B-aligned

typedef __attribute__((ext_vector_type(8))) short short8;
typedef __attribute__((ext_vector_type(4))) float f32x4;

__device__ __forceinline__ unsigned short f2bf(float f) {
    unsigned int u = __float_as_uint(f);
    return (unsigned short)((u + 0x7fffu + ((u >> 16) & 1u)) >> 16);
}

__device__ __forceinline__ void gload_lds16(const void* g, void* l) {
    __builtin_amdgcn_global_load_lds((__attribute__((address_space(1))) void*)g,
                                     (__attribute__((address_space(3))) void*)l,
                                     16, 0, 0);
}

// one kernel converts x, Wqkv, Wo -> contiguous bf16 region
__global__ __launch_bounds__(256)
void cvt_all(const float* __restrict__ x, const float* __restrict__ wqkv,
             const float* __restrict__ wo, unsigned short* __restrict__ out) {
    const int i = blockIdx.x * 256 + threadIdx.x;   // float4 index, grid exact
    const float* src;
    int base;
    if (i < 524288)      { src = x;    base = 0; }
    else if (i < 720896) { src = wqkv; base = 524288; }
    else                 { src = wo;   base = 720896; }
    float4 v = ((const float4*)src)[i - base];
    ((ushort4*)out)[i] = make_ushort4(f2bf(v.x), f2bf(v.y), f2bf(v.z), f2bf(v.w));
}

// qkv projection: 128x64 tiles, 768 blocks. Writes Q,K to qkvh[b][h][ty][s][d]
// and V directly transposed to vT[b][h][d][s].
__global__ __launch_bounds__(256)
void gemm_qkv(const unsigned short* __restrict__ A, const unsigned short* __restrict__ B,
              const float* __restrict__ bias, unsigned short* __restrict__ qkvh,
              unsigned short* __restrict__ vT) {
    constexpr int BM = 128, BN = 64, BK = 32;
    const int K = DIM;
    __shared__ unsigned short As[BM * BK];
    __shared__ unsigned short Bs[BN * BK];
    const int t = threadIdx.x, lane = t & 63, wid = t >> 6;
    const int wr = wid >> 1, wc = wid & 1;
    const int bm = blockIdx.y * BM, bn = blockIdx.x * BN;

    f32x4 acc[4][2];
    #pragma unroll
    for (int m = 0; m < 4; ++m)
        #pragma unroll
        for (int n = 0; n < 2; ++n)
            acc[m][n] = (f32x4){0.f, 0.f, 0.f, 0.f};

    const int lr = lane & 15, lg = lane >> 4, lk = lg * 8;
    for (int kt = 0; kt < K; kt += BK) {
        #pragma unroll
        for (int off = 0; off < BM * BK; off += 2048) {
            const int e = off + t * 8, r = e >> 5, c = e & 31;
            gload_lds16(A + (size_t)(bm + r) * K + kt + c, &As[e]);
        }
        {
            const int e = t * 8, r = e >> 5, c = e & 31;
            gload_lds16(B + (size_t)(bn + r) * K + kt + c, &Bs[e]);
        }
        __syncthreads();
        short8 af[4], bf[2];
        #pragma unroll
        for (int m = 0; m < 4; ++m) af[m] = *(const short8*)&As[(wr * 64 + m * 16 + lr) * BK + lk];
        #pragma unroll
        for (int n = 0; n < 2; ++n) bf[n] = *(const short8*)&Bs[(wc * 32 + n * 16 + lr) * BK + lk];
        #pragma unroll
        for (int m = 0; m < 4; ++m)
            #pragma unroll
            for (int n = 0; n < 2; ++n)
                acc[m][n] = __builtin_amdgcn_mfma_f32_16x16x32_bf16(af[m], bf[n], acc[m][n], 0, 0, 0);
        __syncthreads();
    }

    const int bb = bm >> 11;                  // batch (tile never straddles)
    const int sbase = (bm & 2047) + wr * 64 + lg * 4;
    const int oc0 = bn + wc * 32 + lr;
    #pragma unroll
    for (int n = 0; n < 2; ++n) {
        const int col = oc0 + n * 16;
        const int h = col / 192, rem = col - h * 192;
        const int ty = rem >> 6, d = rem & 63;
        const float bv = bias[col];
        if (ty == 2) {                        // V: packed transposed store
            unsigned short* vrow = vT + ((size_t)(bb * NH + h) * DH + d) * SEQ;
            #pragma unroll
            for (int m = 0; m < 4; ++m) {
                const int s0 = sbase + m * 16;
                ushort4 pk = make_ushort4(f2bf(acc[m][n][0] + bv), f2bf(acc[m][n][1] + bv),
                                          f2bf(acc[m][n][2] + bv), f2bf(acc[m][n][3] + bv));
                *(ushort4*)&vrow[s0] = pk;
            }
        } else {                              // Q,K: scatter
            unsigned short* plane = qkvh + (((size_t)(bb * NH + h) * 3 + ty) * SEQ) * DH + d;
            #pragma unroll
            for (int m = 0; m < 4; ++m)
                #pragma unroll
                for (int r = 0; r < 4; ++r)
                    plane[(size_t)(sbase + m * 16 + r) * DH] = f2bf(acc[m][n][r] + bv);
        }
    }
}

// out[M,N]f32 = A[M,K]bf16 @ B[N,K]bf16^T + bias
template<int BM, int BN, int WR, int WC>
__global__ __launch_bounds__(256)
void gemm_bf16(const unsigned short* __restrict__ A, const unsigned short* __restrict__ B,
               const float* __restrict__ bias, float* __restrict__ C,
               int M, int N, int K) {
    constexpr int BK = 32;
    constexpr int WM = BM / WR, WN = BN / WC;
    constexpr int FM = WM / 16, FN = WN / 16;
    __shared__ unsigned short As[BM * BK];
    __shared__ unsigned short Bs[BN * BK];
    const int t = threadIdx.x, lane = t & 63, wid = t >> 6;
    const int wr = wid / WC, wc = wid % WC;
    const int bm = blockIdx.y * BM, bn = blockIdx.x * BN;

    f32x4 acc[FM][FN];
    #pragma unroll
    for (int m = 0; m < FM; ++m)
        #pragma unroll
        for (int n = 0; n < FN; ++n)
            acc[m][n] = (f32x4){0.f, 0.f, 0.f, 0.f};

    const int lr = lane & 15, lk = (lane >> 4) * 8;
    for (int kt = 0; kt < K; kt += BK) {
        #pragma unroll
        for (int off = 0; off < BM * BK; off += 2048) {
            const int e = off + t * 8, r = e >> 5, c = e & 31;
            gload_lds16(A + (size_t)(bm + r) * K + kt + c, &As[e]);
        }
        #pragma unroll
        for (int off = 0; off < BN * BK; off += 2048) {
            const int e = off + t * 8, r = e >> 5, c = e & 31;
            gload_lds16(B + (size_t)(bn + r) * K + kt + c, &Bs[e]);
        }
        __syncthreads();
        short8 af[FM], bf[FN];
        #pragma unroll
        for (int m = 0; m < FM; ++m) af[m] = *(const short8*)&As[(wr * WM + m * 16 + lr) * BK + lk];
        #pragma unroll
        for (int n = 0; n < FN; ++n) bf[n] = *(const short8*)&Bs[(wc * WN + n * 16 + lr) * BK + lk];
        #pragma unroll
        for (int m = 0; m < FM; ++m)
            #pragma unroll
            for (int n = 0; n < FN; ++n)
                acc[m][n] = __builtin_amdgcn_mfma_f32_16x16x32_bf16(af[m], bf[n], acc[m][n], 0, 0, 0);
        __syncthreads();
    }

    const int orow = bm + wr * WM + (lane >> 4) * 4;
    const int oc0 = bn + wc * WN + (lane & 15);
    #pragma unroll
    for (int m = 0; m < FM; ++m)
        #pragma unroll
        for (int n = 0; n < FN; ++n) {
            const int col = oc0 + n * 16;
            const float bv = bias[col];
            #pragma unroll
            for (int r = 0; r < 4; ++r)
                C[(size_t)(orow + m * 16 + r) * N + col] = acc[m][n][r] + bv;
        }
}

// MFMA windowed attention, LDS-minimal: K/V/Q fragments loaded directly from
// global (L2-resident); only the score/P tile lives in LDS; 2 barriers total.
// One block = (b,h, 16-query tile), 4 waves. 2048 blocks.
__global__ __launch_bounds__(256)
void attn_mfma(const unsigned short* __restrict__ qkvh,
               const unsigned short* __restrict__ vT,
               const int* __restrict__ pad,
               unsigned short* __restrict__ Yb) {
    const int bh = blockIdx.y, b = bh >> 3, h = bh & 7;
    const int i0 = blockIdx.x * QT, kb = i0 - HALF;
    const int t = threadIdx.x, lane = t & 63, w = t >> 6;
    const int lr = lane & 15, lg = lane >> 4;

    __shared__ float Sc[QT * SCS];

    const unsigned short* Qg = qkvh + ((size_t)bh * 3 + 0) * SEQ * DH;
    const unsigned short* Kg = qkvh + ((size_t)bh * 3 + 1) * SEQ * DH;
    const unsigned short* vTg = vT + (size_t)bh * DH * SEQ;
    const int* padb = pad + b * SEQ;

    // Q fragments (A-operand) straight from global
    short8 qf[2];
    #pragma unroll
    for (int kk = 0; kk < 2; ++kk)
        qf[kk] = *(const short8*)&Qg[(size_t)(i0 + lr) * DH + kk * 32 + lg * 8];

    // ---- scores: no barriers, chunks independent ----
    const int k0 = w * 16;
    #pragma unroll
    for (int c = 0; c < 5; ++c) {
        const int nc = (c < 4) ? 64 : 16;
        if (k0 < nc) {
            const int jl = c * 64 + k0 + lr;
            const int j = kb + jl;
            const int jc = j < 0 ? 0 : (j > SEQ - 1 ? SEQ - 1 : j);
            const int kv = (j >= 0 && j < SEQ) ? padb[j] : 0;
            f32x4 a0 = (f32x4){0.f, 0.f, 0.f, 0.f};
            #pragma unroll
            for (int kk = 0; kk < 2; ++kk) {
                const short8 bfr = *(const short8*)&Kg[(size_t)jc * DH + kk * 32 + lg * 8];
                a0 = __builtin_amdgcn_mfma_f32_16x16x32_bf16(qf[kk], bfr, a0, 0, 0, 0);
            }
            #pragma unroll
            for (int r = 0; r < 4; ++r) {
                const int q0 = lg * 4 + r;
                const bool ok = kv && (jl >= q0) && (jl <= q0 + 2 * HALF);
                Sc[q0 * SCS + jl] = ok ? a0[r] * 0.125f : -1e30f;
            }
        }
    }
    __syncthreads();

    // ---- softmax: wave per row (4 rows/wave); bf16 P written in place ----
    for (int r = w; r < QT; r += 4) {
        float* row = &Sc[r * SCS];
        unsigned short* prow = (unsigned short*)row;
        if (!padb[i0 + r]) {
            #pragma unroll
            for (int u = 0; u < 5; ++u) {
                const int jl = lane + 64 * u;
                if (jl < KW) prow[jl] = 0;
            }
            if (lane >= 16 && lane < 32) prow[256 + lane] = 0;   // tail pad
            continue;
        }
        float v[5];
        float mx = -1e30f;
        #pragma unroll
        for (int u = 0; u < 5; ++u) {
            const int jl = lane + 64 * u;
            v[u] = (jl < KW) ? row[jl] : -1e30f;
            mx = fmaxf(mx, v[u]);
        }
        #pragma unroll
        for (int off = 32; off; off >>= 1) mx = fmaxf(mx, __shfl_xor(mx, off));
        float s = 0.f;
        #pragma unroll
        for (int u = 0; u < 5; ++u) { v[u] = __expf(v[u] - mx); s += v[u]; }
        #pragma unroll
        for (int off = 32; off; off >>= 1) s += __shfl_xor(s, off);
        const float inv = 1.f / s;
        asm volatile("" ::: "memory");   // order f32 reads before u16 writes
        #pragma unroll
        for (int u = 0; u < 5; ++u) {
            const int jl = lane + 64 * u;
            if (jl < KW) prow[jl] = f2bf(v[u] * inv);
        }
        if (lane >= 16 && lane < 32) prow[256 + lane] = 0;       // tail pad
    }
    __syncthreads();

    // ---- PV: V fragments direct from vT (L2), P from LDS ----
    f32x4 o0 = (f32x4){0.f, 0.f, 0.f, 0.f};
    const unsigned short* PbU = (const unsigned short*)Sc;
    const int d0 = w * 16 + lr;
    #pragma unroll
    for (int c = 0; c < 5; ++c) {
        const int nkk = (c < 4) ? 2 : 1;
        #pragma unroll
        for (int kk = 0; kk < nkk; ++kk) {
            int j0 = kb + c * 64 + kk * 32 + lg * 8;
            j0 = j0 < 0 ? 0 : (j0 > SEQ - 8 ? SEQ - 8 : j0);   // P=0 off-range
            const short8 vf = *(const short8*)&vTg[(size_t)d0 * SEQ + j0];
            const short8 pf = *(const short8*)&PbU[lr * (SCS * 2) + c * 64 + kk * 32 + lg * 8];
            o0 = __builtin_amdgcn_mfma_f32_16x16x32_bf16(pf, vf, o0, 0, 0, 0);
        }
    }

    #pragma unroll
    for (int r = 0; r < 4; ++r)
        Yb[(size_t)(b * SEQ + i0 + lg * 4 + r) * EMB + h * DH + d0] = f2bf(o0[r]);
}

extern "C" void kernel_launch(void* const* d_in, const int* in_sizes, int n_in,
                              void* d_out, int out_size, void* d_ws, size_t ws_size,
                              hipStream_t stream) {
    const float* x    = (const float*)d_in[0];
    const int*   pad  = (const int*)d_in[1];
    const float* Wqkv = (const float*)d_in[2];
    const float* bqkv = (const float*)d_in[3];
    const float* Wo   = (const float*)d_in[4];
    const float* bo   = (const float*)d_in[5];
    float* out = (float*)d_out;

    const int BS = 2 * SEQ;   // 4096
    char* p = (char*)d_ws;
    unsigned short* qkvh  = (unsigned short*)p;                   // 12.6 MB (Q,K planes used)
    unsigned short* vT    = (unsigned short*)(p + 12582912);      // 4 MB
    unsigned short* xb    = (unsigned short*)(p + 16777216);      // 4 MB (cvt region base)
    unsigned short* wqkvb = (unsigned short*)(p + 20971520);      // 1.5 MB
    unsigned short* wob   = (unsigned short*)(p + 22544384);      // 0.5 MB
    unsigned short* Yb    = xb;   // xb dead after gemm_qkv

    dim3 blk(256);
    cvt_all<<<dim3(3072), blk, 0, stream>>>(x, Wqkv, Wo, xb);
    gemm_qkv<<<dim3(24, 32), blk, 0, stream>>>(xb, wqkvb, bqkv, qkvh, vT);
    attn_mfma<<<dim3(SEQ / QT, 2 * NH), blk, 0, stream>>>(qkvh, vT, pad, Yb);
    gemm_bf16<64, 64, 2, 2><<<dim3(EMB / 64, BS / 64), blk, 0, stream>>>(
        Yb, wob, bo, out, BS, EMB, DIM);
}

// Round 7
// 58.379 us; speedup vs baseline: 11.1455x; 1.0256x over previous
//
#include <hip/hip_runtime.h>

#define NH   8
#define SEQ  2048
#define DIM  512
#define EMB  512
#define DH   64
#define HALF 128
#define QT   16
#define KW   272          // QT + 2*HALF
#define SCS  276          // Sc row stride (f32); 1104B rows, 16B-aligned

typedef __attribute__((ext_vector_type(8))) short short8;
typedef __attribute__((ext_vector_type(4))) float f32x4;

__device__ __forceinline__ unsigned short f2bf(float f) {
    unsigned int u = __float_as_uint(f);
    return (unsigned short)((u + 0x7fffu + ((u >> 16) & 1u)) >> 16);
}

__device__ __forceinline__ void gload_lds16(const void* g, void* l) {
    __builtin_amdgcn_global_load_lds((__attribute__((address_space(1))) void*)g,
                                     (__attribute__((address_space(3))) void*)l,
                                     16, 0, 0);
}

// one kernel converts x, Wqkv, Wo -> contiguous bf16 region
__global__ __launch_bounds__(256)
void cvt_all(const float* __restrict__ x, const float* __restrict__ wqkv,
             const float* __restrict__ wo, unsigned short* __restrict__ out) {
    const int i = blockIdx.x * 256 + threadIdx.x;   // float4 index, grid exact
    const float* src;
    int base;
    if (i < 524288)      { src = x;    base = 0; }
    else if (i < 720896) { src = wqkv; base = 524288; }
    else                 { src = wo;   base = 720896; }
    float4 v = ((const float4*)src)[i - base];
    ((ushort4*)out)[i] = make_ushort4(f2bf(v.x), f2bf(v.y), f2bf(v.z), f2bf(v.w));
}

// qkv projection: 128x64 tiles, BK=64, 768 blocks. Each 64-col tile lies in
// exactly one (h, q/k/v) plane (192 = 3*64). Q,K -> qkvh[b][h][ty][s][d]
// packed; V -> vT[b][h][d][s] packed. LDS A/B tiles XOR-swizzled (source
// pre-swizzle, since global_load_lds writes linearly).
__global__ __launch_bounds__(256)
void gemm_qkv(const unsigned short* __restrict__ A, const unsigned short* __restrict__ B,
              const float* __restrict__ bias, unsigned short* __restrict__ qkvh,
              unsigned short* __restrict__ vT) {
    constexpr int BM = 128, BN = 64, BK = 64;
    __shared__ unsigned short SM[BM * BK + BN * BK];   // 24 KB
    unsigned short* As = SM;            // [128][64] swizzled
    unsigned short* Bs = SM + BM * BK;  // [64][64]  swizzled
    const int t = threadIdx.x, lane = t & 63, wid = t >> 6;
    const int wr = wid >> 1, wc = wid & 1;
    const int bm = blockIdx.y * BM, bn = blockIdx.x * BN;
    const int lr = lane & 15, lg = lane >> 4;

    f32x4 acc[4][2];
    #pragma unroll
    for (int m = 0; m < 4; ++m)
        #pragma unroll
        for (int n = 0; n < 2; ++n)
            acc[m][n] = (f32x4){0.f, 0.f, 0.f, 0.f};

    for (int kt = 0; kt < DIM; kt += BK) {
        #pragma unroll
        for (int off = 0; off < BM * BK; off += 2048) {
            const int e = off + t * 8, r = e >> 6, c4 = (e & 63) >> 3;
            const int gc = (c4 ^ (r & 7)) << 3;
            gload_lds16(A + (size_t)(bm + r) * DIM + kt + gc, &As[e]);
        }
        #pragma unroll
        for (int off = 0; off < BN * BK; off += 2048) {
            const int e = off + t * 8, r = e >> 6, c4 = (e & 63) >> 3;
            const int gc = (c4 ^ (r & 7)) << 3;
            gload_lds16(B + (size_t)(bn + r) * DIM + kt + gc, &Bs[e]);
        }
        __syncthreads();
        short8 af[2][4], bf[2][2];
        #pragma unroll
        for (int kk = 0; kk < 2; ++kk) {
            #pragma unroll
            for (int m = 0; m < 4; ++m) {
                const int row = wr * 64 + m * 16 + lr;
                af[kk][m] = *(const short8*)&As[row * 64 + (((kk * 4 + lg) ^ (row & 7)) << 3)];
            }
            #pragma unroll
            for (int n = 0; n < 2; ++n) {
                const int row = wc * 32 + n * 16 + lr;
                bf[kk][n] = *(const short8*)&Bs[row * 64 + (((kk * 4 + lg) ^ (row & 7)) << 3)];
            }
        }
        #pragma unroll
        for (int kk = 0; kk < 2; ++kk)
            #pragma unroll
            for (int m = 0; m < 4; ++m)
                #pragma unroll
                for (int n = 0; n < 2; ++n)
                    acc[m][n] = __builtin_amdgcn_mfma_f32_16x16x32_bf16(af[kk][m], bf[kk][n], acc[m][n], 0, 0, 0);
        __syncthreads();
    }

    // epilogue: acc -> Tr[128][72] bf16 (reuse SM), then packed stores
    unsigned short* Tr = SM;
    #pragma unroll
    for (int n = 0; n < 2; ++n) {
        const int cl = wc * 32 + n * 16 + lr;
        const float bv = bias[bn + cl];
        #pragma unroll
        for (int m = 0; m < 4; ++m)
            #pragma unroll
            for (int r = 0; r < 4; ++r)
                Tr[(wr * 64 + m * 16 + lg * 4 + r) * 72 + cl] = f2bf(acc[m][n][r] + bv);
    }
    __syncthreads();

    const int h = bn / 192, ty = (bn >> 6) % 3;
    const int bb = bm >> 11, s0 = bm & 2047;
    if (ty < 2) {   // Q,K: contiguous [s][d] rows, 64 B per thread
        unsigned short* plane = qkvh + (((size_t)(bb * NH + h) * 3 + ty) * SEQ) * DH;
        const int s = t >> 1, hf = (t & 1) * 32;
        unsigned short* dst = plane + (size_t)(s0 + s) * DH + hf;
        #pragma unroll
        for (int k8 = 0; k8 < 4; ++k8)
            *(short8*)&dst[k8 * 8] = *(const short8*)&Tr[s * 72 + hf + k8 * 8];
    } else {        // V: transposed packed [d][s] stores
        const int d = t >> 2, p = t & 3;
        unsigned short* vrow = vT + ((size_t)(bb * NH + h) * DH + d) * SEQ + s0 + p * 32;
        #pragma unroll
        for (int k8 = 0; k8 < 4; ++k8) {
            alignas(16) unsigned short tmp[8];
            #pragma unroll
            for (int k = 0; k < 8; ++k) tmp[k] = Tr[(p * 32 + k8 * 8 + k) * 72 + d];
            *(short8*)&vrow[k8 * 8] = *(short8*)tmp;
        }
    }
}

// out[M,N]f32 = A[M,K]bf16 @ B[N,K]bf16^T + bias, swizzled LDS, BK=64
template<int BM, int BN, int BK, int WR, int WC>
__global__ __launch_bounds__(256)
void gemm_bf16(const unsigned short* __restrict__ A, const unsigned short* __restrict__ B,
               const float* __restrict__ bias, float* __restrict__ C,
               int M, int N, int K) {
    constexpr int WM = BM / WR, WN = BN / WC;
    constexpr int FM = WM / 16, FN = WN / 16;
    constexpr int KK = BK / 32;
    __shared__ unsigned short As[BM * BK];
    __shared__ unsigned short Bs[BN * BK];
    const int t = threadIdx.x, lane = t & 63, wid = t >> 6;
    const int wr = wid / WC, wc = wid % WC;
    const int bm = blockIdx.y * BM, bn = blockIdx.x * BN;
    const int lr = lane & 15, lg = lane >> 4;

    f32x4 acc[FM][FN];
    #pragma unroll
    for (int m = 0; m < FM; ++m)
        #pragma unroll
        for (int n = 0; n < FN; ++n)
            acc[m][n] = (f32x4){0.f, 0.f, 0.f, 0.f};

    for (int kt = 0; kt < K; kt += BK) {
        #pragma unroll
        for (int off = 0; off < BM * BK; off += 2048) {
            const int e = off + t * 8, r = e >> 6, c4 = (e & 63) >> 3;
            const int gc = (c4 ^ (r & 7)) << 3;
            gload_lds16(A + (size_t)(bm + r) * K + kt + gc, &As[e]);
        }
        #pragma unroll
        for (int off = 0; off < BN * BK; off += 2048) {
            const int e = off + t * 8, r = e >> 6, c4 = (e & 63) >> 3;
            const int gc = (c4 ^ (r & 7)) << 3;
            gload_lds16(B + (size_t)(bn + r) * K + kt + gc, &Bs[e]);
        }
        __syncthreads();
        short8 af[KK][FM], bf[KK][FN];
        #pragma unroll
        for (int kk = 0; kk < KK; ++kk) {
            #pragma unroll
            for (int m = 0; m < FM; ++m) {
                const int row = wr * WM + m * 16 + lr;
                af[kk][m] = *(const short8*)&As[row * BK + (((kk * 4 + lg) ^ (row & 7)) << 3)];
            }
            #pragma unroll
            for (int n = 0; n < FN; ++n) {
                const int row = wc * WN + n * 16 + lr;
                bf[kk][n] = *(const short8*)&Bs[row * BK + (((kk * 4 + lg) ^ (row & 7)) << 3)];
            }
        }
        #pragma unroll
        for (int kk = 0; kk < KK; ++kk)
            #pragma unroll
            for (int m = 0; m < FM; ++m)
                #pragma unroll
                for (int n = 0; n < FN; ++n)
                    acc[m][n] = __builtin_amdgcn_mfma_f32_16x16x32_bf16(af[kk][m], bf[kk][n], acc[m][n], 0, 0, 0);
        __syncthreads();
    }

    const int orow = bm + wr * WM + lg * 4;
    const int oc0 = bn + wc * WN + lr;
    #pragma unroll
    for (int m = 0; m < FM; ++m)
        #pragma unroll
        for (int n = 0; n < FN; ++n) {
            const int col = oc0 + n * 16;
            const float bv = bias[col];
            #pragma unroll
            for (int r = 0; r < 4; ++r)
                C[(size_t)(orow + m * 16 + r) * N + col] = acc[m][n][r] + bv;
        }
}

// MFMA windowed attention, LDS-minimal: K/V/Q fragments loaded directly from
// global (L2-resident); only the score/P tile lives in LDS; 2 barriers total.
// One block = (b,h, 16-query tile), 4 waves. 2048 blocks.
__global__ __launch_bounds__(256)
void attn_mfma(const unsigned short* __restrict__ qkvh,
               const unsigned short* __restrict__ vT,
               const int* __restrict__ pad,
               unsigned short* __restrict__ Yb) {
    const int bh = blockIdx.y, b = bh >> 3, h = bh & 7;
    const int i0 = blockIdx.x * QT, kb = i0 - HALF;
    const int t = threadIdx.x, lane = t & 63, w = t >> 6;
    const int lr = lane & 15, lg = lane >> 4;

    __shared__ float Sc[QT * SCS];

    const unsigned short* Qg = qkvh + ((size_t)bh * 3 + 0) * SEQ * DH;
    const unsigned short* Kg = qkvh + ((size_t)bh * 3 + 1) * SEQ * DH;
    const unsigned short* vTg = vT + (size_t)bh * DH * SEQ;
    const int* padb = pad + b * SEQ;

    // Q fragments (A-operand) straight from global
    short8 qf[2];
    #pragma unroll
    for (int kk = 0; kk < 2; ++kk)
        qf[kk] = *(const short8*)&Qg[(size_t)(i0 + lr) * DH + kk * 32 + lg * 8];

    // ---- scores: no barriers, chunks independent ----
    const int k0 = w * 16;
    #pragma unroll
    for (int c = 0; c < 5; ++c) {
        const int nc = (c < 4) ? 64 : 16;
        if (k0 < nc) {
            const int jl = c * 64 + k0 + lr;
            const int j = kb + jl;
            const int jc = j < 0 ? 0 : (j > SEQ - 1 ? SEQ - 1 : j);
            const int kv = (j >= 0 && j < SEQ) ? padb[j] : 0;
            f32x4 a0 = (f32x4){0.f, 0.f, 0.f, 0.f};
            #pragma unroll
            for (int kk = 0; kk < 2; ++kk) {
                const short8 bfr = *(const short8*)&Kg[(size_t)jc * DH + kk * 32 + lg * 8];
                a0 = __builtin_amdgcn_mfma_f32_16x16x32_bf16(qf[kk], bfr, a0, 0, 0, 0);
            }
            #pragma unroll
            for (int r = 0; r < 4; ++r) {
                const int q0 = lg * 4 + r;
                const bool ok = kv && (jl >= q0) && (jl <= q0 + 2 * HALF);
                Sc[q0 * SCS + jl] = ok ? a0[r] * 0.125f : -1e30f;
            }
        }
    }
    __syncthreads();

    // ---- softmax: wave per row (4 rows/wave); bf16 P written in place ----
    for (int r = w; r < QT; r += 4) {
        float* row = &Sc[r * SCS];
        unsigned short* prow = (unsigned short*)row;
        if (!padb[i0 + r]) {
            #pragma unroll
            for (int u = 0; u < 5; ++u) {
                const int jl = lane + 64 * u;
                if (jl < KW) prow[jl] = 0;
            }
            if (lane >= 16 && lane < 32) prow[256 + lane] = 0;   // tail pad
            continue;
        }
        float v[5];
        float mx = -1e30f;
        #pragma unroll
        for (int u = 0; u < 5; ++u) {
            const int jl = lane + 64 * u;
            v[u] = (jl < KW) ? row[jl] : -1e30f;
            mx = fmaxf(mx, v[u]);
        }
        #pragma unroll
        for (int off = 32; off; off >>= 1) mx = fmaxf(mx, __shfl_xor(mx, off));
        float s = 0.f;
        #pragma unroll
        for (int u = 0; u < 5; ++u) { v[u] = __expf(v[u] - mx); s += v[u]; }
        #pragma unroll
        for (int off = 32; off; off >>= 1) s += __shfl_xor(s, off);
        const float inv = 1.f / s;
        asm volatile("" ::: "memory");   // order f32 reads before u16 writes
        #pragma unroll
        for (int u = 0; u < 5; ++u) {
            const int jl = lane + 64 * u;
            if (jl < KW) prow[jl] = f2bf(v[u] * inv);
        }
        if (lane >= 16 && lane < 32) prow[256 + lane] = 0;       // tail pad
    }
    __syncthreads();

    // ---- PV: V fragments direct from vT (L2), P from LDS ----
    f32x4 o0 = (f32x4){0.f, 0.f, 0.f, 0.f};
    const unsigned short* PbU = (const unsigned short*)Sc;
    const int d0 = w * 16 + lr;
    #pragma unroll
    for (int c = 0; c < 5; ++c) {
        const int nkk = (c < 4) ? 2 : 1;
        #pragma unroll
        for (int kk = 0; kk < nkk; ++kk) {
            int j0 = kb + c * 64 + kk * 32 + lg * 8;
            j0 = j0 < 0 ? 0 : (j0 > SEQ - 8 ? SEQ - 8 : j0);   // P=0 off-range
            const short8 vf = *(const short8*)&vTg[(size_t)d0 * SEQ + j0];
            const short8 pf = *(const short8*)&PbU[lr * (SCS * 2) + c * 64 + kk * 32 + lg * 8];
            o0 = __builtin_amdgcn_mfma_f32_16x16x32_bf16(pf, vf, o0, 0, 0, 0);
        }
    }

    #pragma unroll
    for (int r = 0; r < 4; ++r)
        Yb[(size_t)(b * SEQ + i0 + lg * 4 + r) * EMB + h * DH + d0] = f2bf(o0[r]);
}

extern "C" void kernel_launch(void* const* d_in, const int* in_sizes, int n_in,
                              void* d_out, int out_size, void* d_ws, size_t ws_size,
                              hipStream_t stream) {
    const float* x    = (const float*)d_in[0];
    const int*   pad  = (const int*)d_in[1];
    const float* Wqkv = (const float*)d_in[2];
    const float* bqkv = (const float*)d_in[3];
    const float* Wo   = (const float*)d_in[4];
    const float* bo   = (const float*)d_in[5];
    float* out = (float*)d_out;

    const int BS = 2 * SEQ;   // 4096
    char* p = (char*)d_ws;
    unsigned short* qkvh  = (unsigned short*)p;                   // 12.6 MB (Q,K planes used)
    unsigned short* vT    = (unsigned short*)(p + 12582912);      // 4 MB
    unsigned short* xb    = (unsigned short*)(p + 16777216);      // 4 MB (cvt region base)
    unsigned short* wqkvb = (unsigned short*)(p + 20971520);      // 1.5 MB
    unsigned short* wob   = (unsigned short*)(p + 22544384);      // 0.5 MB
    unsigned short* Yb    = xb;   // xb dead after gemm_qkv

    dim3 blk(256);
    cvt_all<<<dim3(3072), blk, 0, stream>>>(x, Wqkv, Wo, xb);
    gemm_qkv<<<dim3(24, 32), blk, 0, stream>>>(xb, wqkvb, bqkv, qkvh, vT);
    attn_mfma<<<dim3(SEQ / QT, 2 * NH), blk, 0, stream>>>(qkvh, vT, pad, Yb);
    gemm_bf16<64, 64, 64, 2, 2><<<dim3(EMB / 64, BS / 64), blk, 0, stream>>>(
        Yb, wob, bo, out, BS, EMB, DIM);
}